// Round 1
// baseline (565.757 us; speedup 1.0000x reference)
//
#include <hip/hip_runtime.h>
#include <hip/hip_bf16.h>

#define N_NODES 50000
#define N_EDGES 800000
#define NFEAT   512
#define NHID    64
#define NHEADS  8
#define NCLASS  40
#define HD      (NHEADS*NHID)   // 512
#define ALPHA   0.2f
#define EPS_F   1e-16f
#define NCHUNK  ((N_NODES + 255)/256)   // 196

typedef __attribute__((ext_vector_type(8))) short short8;
typedef __attribute__((ext_vector_type(4))) float floatx4;

__device__ __forceinline__ float bf2f(unsigned short u) {
    union { unsigned int i; float f; } v; v.i = ((unsigned int)u) << 16; return v.f;
}
__device__ __forceinline__ unsigned short f2bf(float f) {
    union { __hip_bfloat16 h; unsigned short u; } cv;
    cv.h = __float2bfloat16(f);
    return cv.u;
}

// ---------------------------------------------------------------------------
// Fused prep: repack W_heads -> Wrb (B^T bf16), W_out -> Wob (padded B^T bf16),
// zero deg. One launch instead of three.
__global__ void prep(const float* __restrict__ Wh, unsigned short* __restrict__ Wrb,
                     const float* __restrict__ Wo, unsigned short* __restrict__ Wob,
                     int* __restrict__ deg) {
    int idx = blockIdx.x*256 + threadIdx.x;      // < 512*512
    if (idx >= 512*512) return;
    if (idx < N_NODES) deg[idx] = 0;
    {
        int n = idx >> 9, k = idx & 511;
        int hd = n >> 6, d = n & 63;
        Wrb[idx] = f2bf(Wh[(size_t)hd*NFEAT*NHID + (size_t)k*NHID + d]);
    }
    if (idx < 64*512) {
        int n = idx >> 9, k = idx & 511;
        float v = (n < NCLASS) ? Wo[(size_t)k*NCLASS + n] : 0.f;
        Wob[idx] = f2bf(v);
    }
}

// ---------------------------------------------------------------------------
// Layer-1 MFMA GEMM. 256 threads, 128x128 tile, XCD swizzle, fused fp32->bf16
// A staging, register-prefetch pipeline.
// Output permuted: H1p[row*512 + d*8 + hd] (col c = hd*64+d).
__global__ __launch_bounds__(256) void mfma_gemm1(const float* __restrict__ A,
                                                  const unsigned short* __restrict__ Bbf,
                                                  unsigned short* __restrict__ H1p, int M) {
    int id = blockIdx.x;
    int rb = (id >> 5)*8 + (id & 7);     // row tile (XCD swizzle)
    int cb = (id >> 3) & 3;
    int row0 = rb * 128, col0 = cb * 128;
    if (row0 >= M) return;

    __shared__ short Asl[128*40];
    __shared__ short Bsl[128*40];
    int tid  = threadIdx.x;
    int wid  = tid >> 6, lane = tid & 63;
    int lrow = lane & 15, quad = lane >> 4;
    int wm = wid & 1, wn = wid >> 1;

    int sr[2], sk[2];
#pragma unroll
    for (int it = 0; it < 2; ++it) {
        int q = tid + it*256;
        sr[it] = q >> 2; sk[it] = (q & 3) * 8;
    }
    int arow[2];
#pragma unroll
    for (int it = 0; it < 2; ++it) {
        int ar = row0 + sr[it];
        arow[it] = ar < M ? ar : M - 1;
    }

    floatx4 acc[4][4];
#pragma unroll
    for (int mm = 0; mm < 4; mm++)
#pragma unroll
        for (int nn = 0; nn < 4; nn++) acc[mm][nn] = (floatx4){0.f,0.f,0.f,0.f};

    float4 fa[2][2];
    short8 fb[2];
#pragma unroll
    for (int it = 0; it < 2; ++it) {
        const float* src = A + (size_t)arow[it]*512 + sk[it];
        fa[it][0] = *(const float4*)src;
        fa[it][1] = *(const float4*)(src + 4);
        fb[it] = *(const short8*)(Bbf + (size_t)(col0 + sr[it])*512 + sk[it]);
    }

    for (int k0 = 0; k0 < 512; k0 += 32) {
#pragma unroll
        for (int it = 0; it < 2; ++it) {
            short8 h;
            h[0] = (short)f2bf(fa[it][0].x); h[1] = (short)f2bf(fa[it][0].y);
            h[2] = (short)f2bf(fa[it][0].z); h[3] = (short)f2bf(fa[it][0].w);
            h[4] = (short)f2bf(fa[it][1].x); h[5] = (short)f2bf(fa[it][1].y);
            h[6] = (short)f2bf(fa[it][1].z); h[7] = (short)f2bf(fa[it][1].w);
            *(short8*)(&Asl[sr[it]*40 + sk[it]]) = h;
            *(short8*)(&Bsl[sr[it]*40 + sk[it]]) = fb[it];
        }
        __syncthreads();
        if (k0 + 32 < 512) {
            int kn = k0 + 32;
#pragma unroll
            for (int it = 0; it < 2; ++it) {
                const float* src = A + (size_t)arow[it]*512 + kn + sk[it];
                fa[it][0] = *(const float4*)src;
                fa[it][1] = *(const float4*)(src + 4);
                fb[it] = *(const short8*)(Bbf + (size_t)(col0 + sr[it])*512 + kn + sk[it]);
            }
        }
        short8 af[4], bfr[4];
#pragma unroll
        for (int mm = 0; mm < 4; ++mm)
            af[mm] = *(const short8*)(&Asl[(wm*64 + mm*16 + lrow)*40 + quad*8]);
#pragma unroll
        for (int nn = 0; nn < 4; ++nn)
            bfr[nn] = *(const short8*)(&Bsl[(wn*64 + nn*16 + lrow)*40 + quad*8]);
#pragma unroll
        for (int mm = 0; mm < 4; ++mm)
#pragma unroll
            for (int nn = 0; nn < 4; ++nn)
                acc[mm][nn] = __builtin_amdgcn_mfma_f32_16x16x32_bf16(
                    af[mm], bfr[nn], acc[mm][nn], 0, 0, 0);
        __syncthreads();
    }

#pragma unroll
    for (int mm = 0; mm < 4; ++mm) {
        int rbase = row0 + wm*64 + mm*16 + quad*4;
#pragma unroll
        for (int nn = 0; nn < 4; ++nn) {
            int c = col0 + wn*64 + nn*16 + lrow;
            int off = (c & 63)*8 + (c >> 6);     // permuted layout
#pragma unroll
            for (int r = 0; r < 4; ++r) {
                int grow = rbase + r;
                if (grow < M)
                    H1p[(size_t)grow*512 + off] = f2bf(acc[mm][nn][r]);
            }
        }
    }
}

// ---------------------------------------------------------------------------
// Layer-2 MFMA GEMM: H2p[M,64] = hcatb[M,512] @ Woutb^T (cols 40..63 zero).
__global__ __launch_bounds__(256) void mfma_gemm2(const unsigned short* __restrict__ Abf,
                                                  const unsigned short* __restrict__ Bbf,
                                                  float* __restrict__ H2p, int M) {
    __shared__ short Asl[256*40];
    __shared__ short Bsl[64*40];
    int tid  = threadIdx.x;
    int wid  = tid >> 6, lane = tid & 63;
    int lrow = lane & 15, quad = lane >> 4;
    int row0 = blockIdx.x * 256;

    floatx4 acc[4][4];
#pragma unroll
    for (int mm = 0; mm < 4; mm++)
#pragma unroll
        for (int nn = 0; nn < 4; nn++) acc[mm][nn] = (floatx4){0.f,0.f,0.f,0.f};

    for (int k0 = 0; k0 < 512; k0 += 32) {
#pragma unroll
        for (int it = 0; it < 4; ++it) {
            int q  = tid + it*256;
            int r  = q >> 2, kk = (q & 3) * 8;
            int ar = row0 + r; ar = ar < M ? ar : M - 1;
            *(short8*)(&Asl[r*40 + kk]) =
                *(const short8*)(Abf + (size_t)ar*512 + k0 + kk);
        }
        {
            int r = tid >> 2, kk = (tid & 3) * 8;
            *(short8*)(&Bsl[r*40 + kk]) =
                *(const short8*)(Bbf + (size_t)r*512 + k0 + kk);
        }
        __syncthreads();
        short8 af[4], bfr[4];
#pragma unroll
        for (int mm = 0; mm < 4; ++mm)
            af[mm] = *(const short8*)(&Asl[(wid*64 + mm*16 + lrow)*40 + quad*8]);
#pragma unroll
        for (int nn = 0; nn < 4; ++nn)
            bfr[nn] = *(const short8*)(&Bsl[(nn*16 + lrow)*40 + quad*8]);
#pragma unroll
        for (int mm = 0; mm < 4; ++mm)
#pragma unroll
            for (int nn = 0; nn < 4; ++nn)
                acc[mm][nn] = __builtin_amdgcn_mfma_f32_16x16x32_bf16(
                    af[mm], bfr[nn], acc[mm][nn], 0, 0, 0);
        __syncthreads();
    }

#pragma unroll
    for (int mm = 0; mm < 4; ++mm) {
        int rbase = row0 + wid*64 + mm*16 + quad*4;
#pragma unroll
        for (int nn = 0; nn < 4; ++nn) {
            int c = nn*16 + lrow;
#pragma unroll
            for (int r = 0; r < 4; ++r) {
                int grow = rbase + r;
                if (grow < M)
                    H2p[(size_t)grow*64 + c] = acc[mm][nn][r];
            }
        }
    }
}

// ---------------------------------------------------------------------------
// Attention dots from PERMUTED H1p. One wave per node; lane = feature d.
__global__ __launch_bounds__(256) void dots1(const unsigned short* __restrict__ H1p,
                                             const float* __restrict__ a_heads,
                                             float* __restrict__ srcdot,
                                             float* __restrict__ dstdot) {
    int wave = (blockIdx.x*256 + threadIdx.x) >> 6;
    int lane = threadIdx.x & 63;
    if (wave >= N_NODES) return;
    short8 hv = *(const short8*)(H1p + (size_t)wave*512 + lane*8);
    float s0[8], s1[8];
#pragma unroll
    for (int j = 0; j < 8; j++) {
        float h = bf2f((unsigned short)hv[j]);
        s0[j] = h * a_heads[j*128 + lane];
        s1[j] = h * a_heads[j*128 + 64 + lane];
    }
#pragma unroll
    for (int off = 32; off > 0; off >>= 1) {
#pragma unroll
        for (int j = 0; j < 8; j++) {
            s0[j] += __shfl_down(s0[j], off, 64);
            s1[j] += __shfl_down(s1[j], off, 64);
        }
    }
    if (lane == 0) {
#pragma unroll
        for (int j = 0; j < 8; j++) {
            srcdot[wave*8 + j] = s0[j];
            dstdot[wave*8 + j] = s1[j];
        }
    }
}

// ---------------------------------------------------------------------------
// CSR build
__global__ void histk(const int* __restrict__ row, int* __restrict__ deg) {
    int e = blockIdx.x*256 + threadIdx.x;
    if (e < N_EDGES) atomicAdd(&deg[row[e]], 1);
}
__global__ void scanA(const int* __restrict__ deg, int* __restrict__ row_ptr,
                      int* __restrict__ chunk_tot) {
    __shared__ int s[256];
    int t = threadIdx.x;
    int idx = blockIdx.x*256 + t;
    int v = (idx < N_NODES) ? deg[idx] : 0;
    s[t] = v;
    __syncthreads();
#pragma unroll
    for (int off = 1; off < 256; off <<= 1) {
        int x = (t >= off) ? s[t-off] : 0;
        __syncthreads();
        s[t] += x;
        __syncthreads();
    }
    if (idx < N_NODES) row_ptr[idx] = s[t] - v;
    if (t == 255) chunk_tot[blockIdx.x] = s[t];
}
__global__ void scanB(const int* __restrict__ chunk_tot, int* __restrict__ chunk_off,
                      int* __restrict__ row_ptr) {
    __shared__ int s[256];
    int t = threadIdx.x;
    int v = (t < NCHUNK) ? chunk_tot[t] : 0;
    s[t] = v;
    __syncthreads();
#pragma unroll
    for (int off = 1; off < 256; off <<= 1) {
        int x = (t >= off) ? s[t-off] : 0;
        __syncthreads();
        s[t] += x;
        __syncthreads();
    }
    if (t < NCHUNK) chunk_off[t] = s[t] - v;
    if (t == 255) row_ptr[N_NODES] = s[t];
}
__global__ void scanC(const int* __restrict__ chunk_off, int* __restrict__ row_ptr,
                      int* __restrict__ cursor) {
    int idx = blockIdx.x*256 + threadIdx.x;
    if (idx < N_NODES) {
        int rp = row_ptr[idx] + chunk_off[idx >> 8];
        row_ptr[idx] = rp;
        cursor[idx] = rp;
    }
}

// CSR fill only (edge weights are recomputed in agg1 from srcdot/dstdot).
__global__ void fillk(const int* __restrict__ row, const int* __restrict__ col,
                      int* __restrict__ cursor, int* __restrict__ csr_col) {
    int e = blockIdx.x*256 + threadIdx.x;
    if (e >= N_EDGES) return;
    int r = row[e], c = col[e];
    int pos = atomicAdd(&cursor[r], 1);
    csr_col[pos] = c;
}

// ---------------------------------------------------------------------------
// Layer-1 aggregation + ELU, software-pipelined.
//  * all col indices of the node preloaded into one register (colreg) -> no
//    csr_col load on the gather critical path (readlane extracts them)
//  * 2-color x 3-edge batches: batch B's 9 loads are issued before batch A is
//    consumed, so ~18 loads stay in flight per wave (vs 12 with a full drain)
//  * edge weight w = exp(-lrelu(srcdot[r]+dstdot[c])) recomputed here
//    (bit-identical to the old fillk_w1 math) -> Wcsr buffer eliminated.
__global__ __launch_bounds__(256) void agg1(const unsigned short* __restrict__ H1p,
                                            const float* __restrict__ srcdot,
                                            const float* __restrict__ dstdot,
                                            const int* __restrict__ row_ptr,
                                            const int* __restrict__ csr_col,
                                            unsigned short* __restrict__ hcatb) {
    int wave = (blockIdx.x*256 + threadIdx.x) >> 6;
    int lane = threadIdx.x & 63;
    if (wave >= N_NODES) return;
    int start = row_ptr[wave], end = row_ptr[wave+1];
    int deg = end - start;

    float4 sa = *(const float4*)(srcdot + (size_t)wave*8);
    float4 sb = *(const float4*)(srcdot + (size_t)wave*8 + 4);
    float sd0 = sa.x, sd1 = sa.y, sd2 = sa.z, sd3 = sa.w;
    float sd4 = sb.x, sd5 = sb.y, sd6 = sb.z, sd7 = sb.w;

    float acc0=0.f,acc1=0.f,acc2=0.f,acc3=0.f,acc4=0.f,acc5=0.f,acc6=0.f,acc7=0.f;
    float den0=0.f,den1=0.f,den2=0.f,den3=0.f,den4=0.f,den5=0.f,den6=0.f,den7=0.f;

    int colreg = 0;
    if (deg > 0) colreg = csr_col[start + (lane < deg ? lane : deg - 1)];

#define CONS1(H, D0, D1) do { \
    float t0_=sd0+(D0).x, t1_=sd1+(D0).y, t2_=sd2+(D0).z, t3_=sd3+(D0).w; \
    float t4_=sd4+(D1).x, t5_=sd5+(D1).y, t6_=sd6+(D1).z, t7_=sd7+(D1).w; \
    t0_ = t0_>0.f?t0_:ALPHA*t0_; t1_ = t1_>0.f?t1_:ALPHA*t1_; \
    t2_ = t2_>0.f?t2_:ALPHA*t2_; t3_ = t3_>0.f?t3_:ALPHA*t3_; \
    t4_ = t4_>0.f?t4_:ALPHA*t4_; t5_ = t5_>0.f?t5_:ALPHA*t5_; \
    t6_ = t6_>0.f?t6_:ALPHA*t6_; t7_ = t7_>0.f?t7_:ALPHA*t7_; \
    float w0_=__expf(-t0_), w1_=__expf(-t1_), w2_=__expf(-t2_), w3_=__expf(-t3_); \
    float w4_=__expf(-t4_), w5_=__expf(-t5_), w6_=__expf(-t6_), w7_=__expf(-t7_); \
    den0+=w0_; acc0=fmaf(w0_, bf2f((unsigned short)(H)[0]), acc0); \
    den1+=w1_; acc1=fmaf(w1_, bf2f((unsigned short)(H)[1]), acc1); \
    den2+=w2_; acc2=fmaf(w2_, bf2f((unsigned short)(H)[2]), acc2); \
    den3+=w3_; acc3=fmaf(w3_, bf2f((unsigned short)(H)[3]), acc3); \
    den4+=w4_; acc4=fmaf(w4_, bf2f((unsigned short)(H)[4]), acc4); \
    den5+=w5_; acc5=fmaf(w5_, bf2f((unsigned short)(H)[5]), acc5); \
    den6+=w6_; acc6=fmaf(w6_, bf2f((unsigned short)(H)[6]), acc6); \
    den7+=w7_; acc7=fmaf(w7_, bf2f((unsigned short)(H)[7]), acc7); \
} while(0)

#define GATH3(HS0,HS1,HS2,P0,P1,P2,P3,P4,P5,BASE) do { \
    int cg0_ = __builtin_amdgcn_readlane(colreg, (BASE)); \
    int cg1_ = __builtin_amdgcn_readlane(colreg, (BASE)+1); \
    int cg2_ = __builtin_amdgcn_readlane(colreg, (BASE)+2); \
    HS0 = *(const short8*)(H1p + (size_t)cg0_*512 + lane*8); \
    P0  = *(const float4*)(dstdot + (size_t)cg0_*8); \
    P1  = *(const float4*)(dstdot + (size_t)cg0_*8 + 4); \
    HS1 = *(const short8*)(H1p + (size_t)cg1_*512 + lane*8); \
    P2  = *(const float4*)(dstdot + (size_t)cg1_*8); \
    P3  = *(const float4*)(dstdot + (size_t)cg1_*8 + 4); \
    HS2 = *(const short8*)(H1p + (size_t)cg2_*512 + lane*8); \
    P4  = *(const float4*)(dstdot + (size_t)cg2_*8); \
    P5  = *(const float4*)(dstdot + (size_t)cg2_*8 + 4); \
} while(0)

#define CONS3(HS0,HS1,HS2,P0,P1,P2,P3,P4,P5) do { \
    CONS1(HS0,P0,P1); CONS1(HS1,P2,P3); CONS1(HS2,P4,P5); } while(0)

    int lim = deg < 64 ? deg : 64;
    int nb = lim / 3;
    int k = start;
    short8 ha0, ha1, ha2, hb0, hb1, hb2;
    float4 pa0, pa1, pa2, pa3, pa4, pa5;
    float4 pb0, pb1, pb2, pb3, pb4, pb5;
    if (nb > 0) {
        GATH3(ha0,ha1,ha2, pa0,pa1,pa2,pa3,pa4,pa5, 0);
        int b = 1;
        for (; b + 1 < nb; b += 2) {
            GATH3(hb0,hb1,hb2, pb0,pb1,pb2,pb3,pb4,pb5, b*3);
            CONS3(ha0,ha1,ha2, pa0,pa1,pa2,pa3,pa4,pa5);
            GATH3(ha0,ha1,ha2, pa0,pa1,pa2,pa3,pa4,pa5, (b+1)*3);
            CONS3(hb0,hb1,hb2, pb0,pb1,pb2,pb3,pb4,pb5);
        }
        if (b < nb) {
            GATH3(hb0,hb1,hb2, pb0,pb1,pb2,pb3,pb4,pb5, b*3);
            CONS3(ha0,ha1,ha2, pa0,pa1,pa2,pa3,pa4,pa5);
            CONS3(hb0,hb1,hb2, pb0,pb1,pb2,pb3,pb4,pb5);
        } else {
            CONS3(ha0,ha1,ha2, pa0,pa1,pa2,pa3,pa4,pa5);
        }
        k = start + nb*3;
    }
    for (; k < end; ++k) {
        int c_ = (k - start < 64) ? __builtin_amdgcn_readlane(colreg, k - start)
                                  : csr_col[k];
        short8 hv = *(const short8*)(H1p + (size_t)c_*512 + lane*8);
        float4 d0 = *(const float4*)(dstdot + (size_t)c_*8);
        float4 d1 = *(const float4*)(dstdot + (size_t)c_*8 + 4);
        CONS1(hv, d0, d1);
    }
#undef GATH3
#undef CONS3

    {
        float o, dsum;
        float accv[8] = {acc0,acc1,acc2,acc3,acc4,acc5,acc6,acc7};
        float denv[8] = {den0,den1,den2,den3,den4,den5,den6,den7};
#pragma unroll
        for (int j = 0; j < 8; j++) {
            dsum = denv[j];
            o = accv[j] / (dsum + EPS_F);
            o = o > 0.f ? o : (__expf(o) - 1.f);   // ELU
            hcatb[(size_t)wave*HD + j*64 + lane] = f2bf(o);
        }
    }
#undef CONS1
}

// ---------------------------------------------------------------------------
// Final attention dots: one wave per node, coalesced H2p row read + shuffle
// reduce (replaces stride-64 scalar loop).
__global__ __launch_bounds__(256) void dots2(const float* __restrict__ H2p,
                                             const float* __restrict__ a_out,
                                             float* __restrict__ src2,
                                             float* __restrict__ dst2) {
    int wave = (blockIdx.x*256 + threadIdx.x) >> 6;
    int lane = threadIdx.x & 63;
    if (wave >= N_NODES) return;
    float h  = H2p[(size_t)wave*64 + lane];
    float a0 = lane < NCLASS ? a_out[lane] : 0.f;
    float a1 = lane < NCLASS ? a_out[NCLASS + lane] : 0.f;
    float s0 = h * a0, s1 = h * a1;
#pragma unroll
    for (int off = 32; off > 0; off >>= 1) {
        s0 += __shfl_down(s0, off, 64);
        s1 += __shfl_down(s1, off, 64);
    }
    if (lane == 0) { src2[wave] = s0; dst2[wave] = s1; }
}

// ---------------------------------------------------------------------------
// Final aggregation, software-pipelined like agg1 (8-edge x 2-color batches;
// per-edge state is 2 floats so registers stay cheap).
__global__ __launch_bounds__(256) void agg2(const float* __restrict__ H2p,
                                            const float* __restrict__ src2,
                                            const float* __restrict__ dst2,
                                            const int* __restrict__ row_ptr,
                                            const int* __restrict__ csr_col,
                                            float* __restrict__ out) {
    int wave = (blockIdx.x*256 + threadIdx.x) >> 6;
    int lane = threadIdx.x & 63;
    if (wave >= N_NODES) return;
    int start = row_ptr[wave], end = row_ptr[wave+1];
    int deg = end - start;
    float s2i = src2[wave];
    int l = lane < NCLASS ? lane : 0;
    float acc = 0.f, den = 0.f;

    int colreg = 0;
    if (deg > 0) colreg = csr_col[start + (lane < deg ? lane : deg - 1)];

#define AG2_G1(T, H, IDX) do { \
    int cg_ = __builtin_amdgcn_readlane(colreg, (IDX)); \
    T = dst2[cg_]; \
    H = H2p[(size_t)cg_*64 + l]; \
} while(0)
#define AG2_C1(T, H) do { \
    float t_ = s2i + (T); \
    t_ = t_ > 0.f ? t_ : ALPHA*t_; \
    float w_ = __expf(-t_); \
    den += w_; acc = fmaf(w_, (H), acc); \
} while(0)
#define AG2_G8(T0,T1,T2,T3,T4,T5,T6,T7,H0,H1,H2,H3,H4,H5,H6,H7,BASE) do { \
    AG2_G1(T0,H0,(BASE));   AG2_G1(T1,H1,(BASE)+1); \
    AG2_G1(T2,H2,(BASE)+2); AG2_G1(T3,H3,(BASE)+3); \
    AG2_G1(T4,H4,(BASE)+4); AG2_G1(T5,H5,(BASE)+5); \
    AG2_G1(T6,H6,(BASE)+6); AG2_G1(T7,H7,(BASE)+7); \
} while(0)
#define AG2_C8(T0,T1,T2,T3,T4,T5,T6,T7,H0,H1,H2,H3,H4,H5,H6,H7) do { \
    AG2_C1(T0,H0); AG2_C1(T1,H1); AG2_C1(T2,H2); AG2_C1(T3,H3); \
    AG2_C1(T4,H4); AG2_C1(T5,H5); AG2_C1(T6,H6); AG2_C1(T7,H7); \
} while(0)

    int lim = deg < 64 ? deg : 64;
    int nb = lim >> 3;
    int k = start;
    float ta0,ta1,ta2,ta3,ta4,ta5,ta6,ta7, ga0,ga1,ga2,ga3,ga4,ga5,ga6,ga7;
    float tb0,tb1,tb2,tb3,tb4,tb5,tb6,tb7, gb0,gb1,gb2,gb3,gb4,gb5,gb6,gb7;
    if (nb > 0) {
        AG2_G8(ta0,ta1,ta2,ta3,ta4,ta5,ta6,ta7, ga0,ga1,ga2,ga3,ga4,ga5,ga6,ga7, 0);
        int b = 1;
        for (; b + 1 < nb; b += 2) {
            AG2_G8(tb0,tb1,tb2,tb3,tb4,tb5,tb6,tb7, gb0,gb1,gb2,gb3,gb4,gb5,gb6,gb7, b*8);
            AG2_C8(ta0,ta1,ta2,ta3,ta4,ta5,ta6,ta7, ga0,ga1,ga2,ga3,ga4,ga5,ga6,ga7);
            AG2_G8(ta0,ta1,ta2,ta3,ta4,ta5,ta6,ta7, ga0,ga1,ga2,ga3,ga4,ga5,ga6,ga7, (b+1)*8);
            AG2_C8(tb0,tb1,tb2,tb3,tb4,tb5,tb6,tb7, gb0,gb1,gb2,gb3,gb4,gb5,gb6,gb7);
        }
        if (b < nb) {
            AG2_G8(tb0,tb1,tb2,tb3,tb4,tb5,tb6,tb7, gb0,gb1,gb2,gb3,gb4,gb5,gb6,gb7, b*8);
            AG2_C8(ta0,ta1,ta2,ta3,ta4,ta5,ta6,ta7, ga0,ga1,ga2,ga3,ga4,ga5,ga6,ga7);
            AG2_C8(tb0,tb1,tb2,tb3,tb4,tb5,tb6,tb7, gb0,gb1,gb2,gb3,gb4,gb5,gb6,gb7);
        } else {
            AG2_C8(ta0,ta1,ta2,ta3,ta4,ta5,ta6,ta7, ga0,ga1,ga2,ga3,ga4,ga5,ga6,ga7);
        }
        k = start + nb*8;
    }
    for (; k < end; ++k) {
        int c_ = (k - start < 64) ? __builtin_amdgcn_readlane(colreg, k - start)
                                  : csr_col[k];
        float t = dst2[c_];
        float h = H2p[(size_t)c_*64 + l];
        AG2_C1(t, h);
    }
#undef AG2_G1
#undef AG2_C1
#undef AG2_G8
#undef AG2_C8

    if (lane < NCLASS)
        out[(size_t)wave*NCLASS + lane] = acc / (den + EPS_F);
}

// ---------------------------------------------------------------------------
extern "C" void kernel_launch(void* const* d_in, const int* in_sizes, int n_in,
                              void* d_out, int out_size, void* d_ws, size_t ws_size,
                              hipStream_t stream) {
    const float* x       = (const float*)d_in[0];
    const float* W_heads = (const float*)d_in[1];
    const float* a_heads = (const float*)d_in[2];
    const float* W_out   = (const float*)d_in[3];
    const float* a_out   = (const float*)d_in[4];
    const int*   ei      = (const int*)d_in[5];
    const int*   row     = ei;
    const int*   col     = ei + N_EDGES;
    float* out = (float*)d_out;

    char* ws = (char*)d_ws;
    size_t off = 0;
    auto alloc = [&](size_t bytes) {
        char* p = ws + off;
        off = (off + bytes + 255) & ~(size_t)255;
        return p;
    };
    unsigned short* Wrb   = (unsigned short*)alloc((size_t)512*512*2);
    unsigned short* Wob   = (unsigned short*)alloc((size_t)64*512*2);
    unsigned short* H1p   = (unsigned short*)alloc((size_t)N_NODES*HD*2);
    unsigned short* hcatb = (unsigned short*)alloc((size_t)N_NODES*HD*2);
    float* srcdot  = (float*)alloc((size_t)N_NODES*NHEADS*4);
    float* dstdot  = (float*)alloc((size_t)N_NODES*NHEADS*4);
    int*   deg     = (int*)alloc((size_t)N_NODES*4);
    int*   row_ptr = (int*)alloc((size_t)(N_NODES+1)*4);
    int*   cursor  = (int*)alloc((size_t)N_NODES*4);
    int*   ctot    = (int*)alloc(256*4);
    int*   coff    = (int*)alloc(256*4);
    int*   csr_col = (int*)alloc((size_t)N_EDGES*4);
    float* H2p     = (float*)alloc((size_t)N_NODES*64*4);
    float* src2    = (float*)alloc((size_t)N_NODES*4);
    float* dst2    = (float*)alloc((size_t)N_NODES*4);
    (void)ws_size;

    const int EB = (N_EDGES + 255)/256;
    const int WB = (N_NODES*64 + 255)/256;   // wave-per-node grids

    // Layer 1
    prep<<<(512*512 + 255)/256, 256, 0, stream>>>(W_heads, Wrb, W_out, Wob, deg);
    {
        int rtiles = (N_NODES + 127)/128;            // 391
        int nblk = ((rtiles + 7)/8) * 32;            // 1568
        mfma_gemm1<<<nblk, 256, 0, stream>>>(x, Wrb, H1p, N_NODES);
    }
    dots1<<<WB, 256, 0, stream>>>(H1p, a_heads, srcdot, dstdot);

    // CSR build
    histk<<<EB, 256, 0, stream>>>(row, deg);
    scanA<<<NCHUNK, 256, 0, stream>>>(deg, row_ptr, ctot);
    scanB<<<1, 256, 0, stream>>>(ctot, coff, row_ptr);
    scanC<<<NCHUNK, 256, 0, stream>>>(coff, row_ptr, cursor);
    fillk<<<EB, 256, 0, stream>>>(row, col, cursor, csr_col);

    agg1<<<WB, 256, 0, stream>>>(H1p, srcdot, dstdot, row_ptr, csr_col, hcatb);

    // Layer 2
    mfma_gemm2<<<(N_NODES + 255)/256, 256, 0, stream>>>(hcatb, Wob, H2p, N_NODES);
    dots2<<<WB, 256, 0, stream>>>(H2p, a_out, src2, dst2);
    agg2<<<WB, 256, 0, stream>>>(H2p, src2, dst2, row_ptr, csr_col, out);
}

// Round 2
// 556.778 us; speedup vs baseline: 1.0161x; 1.0161x over previous
//
#include <hip/hip_runtime.h>
#include <hip/hip_bf16.h>

#define N_NODES 50000
#define N_EDGES 800000
#define NFEAT   512
#define NHID    64
#define NHEADS  8
#define NCLASS  40
#define HD      (NHEADS*NHID)   // 512
#define ALPHA   0.2f
#define EPS_F   1e-16f
#define NCHUNK  ((N_NODES + 255)/256)   // 196

typedef __attribute__((ext_vector_type(8))) short short8;
typedef __attribute__((ext_vector_type(4))) float floatx4;

__device__ __forceinline__ float bf2f(unsigned short u) {
    union { unsigned int i; float f; } v; v.i = ((unsigned int)u) << 16; return v.f;
}
__device__ __forceinline__ unsigned short f2bf(float f) {
    union { __hip_bfloat16 h; unsigned short u; } cv;
    cv.h = __float2bfloat16(f);
    return cv.u;
}

// ---------------------------------------------------------------------------
// Fused prep: repack W_heads -> Wrb (B^T bf16), W_out -> Wob (padded B^T bf16),
// zero deg. One launch instead of three.
__global__ void prep(const float* __restrict__ Wh, unsigned short* __restrict__ Wrb,
                     const float* __restrict__ Wo, unsigned short* __restrict__ Wob,
                     int* __restrict__ deg) {
    int idx = blockIdx.x*256 + threadIdx.x;      // < 512*512
    if (idx >= 512*512) return;
    if (idx < N_NODES) deg[idx] = 0;
    {
        int n = idx >> 9, k = idx & 511;
        int hd = n >> 6, d = n & 63;
        Wrb[idx] = f2bf(Wh[(size_t)hd*NFEAT*NHID + (size_t)k*NHID + d]);
    }
    if (idx < 64*512) {
        int n = idx >> 9, k = idx & 511;
        float v = (n < NCLASS) ? Wo[(size_t)k*NCLASS + n] : 0.f;
        Wob[idx] = f2bf(v);
    }
}

// ---------------------------------------------------------------------------
// Layer-1 MFMA GEMM. 256 threads, 128x128 tile, XCD swizzle, fused fp32->bf16
// A staging, register-prefetch pipeline.
// Output permuted: H1p[row*512 + d*8 + hd] (col c = hd*64+d).
__global__ __launch_bounds__(256) void mfma_gemm1(const float* __restrict__ A,
                                                  const unsigned short* __restrict__ Bbf,
                                                  unsigned short* __restrict__ H1p, int M) {
    int id = blockIdx.x;
    int rb = (id >> 5)*8 + (id & 7);     // row tile (XCD swizzle)
    int cb = (id >> 3) & 3;
    int row0 = rb * 128, col0 = cb * 128;
    if (row0 >= M) return;

    __shared__ short Asl[128*40];
    __shared__ short Bsl[128*40];
    int tid  = threadIdx.x;
    int wid  = tid >> 6, lane = tid & 63;
    int lrow = lane & 15, quad = lane >> 4;
    int wm = wid & 1, wn = wid >> 1;

    int sr[2], sk[2];
#pragma unroll
    for (int it = 0; it < 2; ++it) {
        int q = tid + it*256;
        sr[it] = q >> 2; sk[it] = (q & 3) * 8;
    }
    int arow[2];
#pragma unroll
    for (int it = 0; it < 2; ++it) {
        int ar = row0 + sr[it];
        arow[it] = ar < M ? ar : M - 1;
    }

    floatx4 acc[4][4];
#pragma unroll
    for (int mm = 0; mm < 4; mm++)
#pragma unroll
        for (int nn = 0; nn < 4; nn++) acc[mm][nn] = (floatx4){0.f,0.f,0.f,0.f};

    float4 fa[2][2];
    short8 fb[2];
#pragma unroll
    for (int it = 0; it < 2; ++it) {
        const float* src = A + (size_t)arow[it]*512 + sk[it];
        fa[it][0] = *(const float4*)src;
        fa[it][1] = *(const float4*)(src + 4);
        fb[it] = *(const short8*)(Bbf + (size_t)(col0 + sr[it])*512 + sk[it]);
    }

    for (int k0 = 0; k0 < 512; k0 += 32) {
#pragma unroll
        for (int it = 0; it < 2; ++it) {
            short8 h;
            h[0] = (short)f2bf(fa[it][0].x); h[1] = (short)f2bf(fa[it][0].y);
            h[2] = (short)f2bf(fa[it][0].z); h[3] = (short)f2bf(fa[it][0].w);
            h[4] = (short)f2bf(fa[it][1].x); h[5] = (short)f2bf(fa[it][1].y);
            h[6] = (short)f2bf(fa[it][1].z); h[7] = (short)f2bf(fa[it][1].w);
            *(short8*)(&Asl[sr[it]*40 + sk[it]]) = h;
            *(short8*)(&Bsl[sr[it]*40 + sk[it]]) = fb[it];
        }
        __syncthreads();
        if (k0 + 32 < 512) {
            int kn = k0 + 32;
#pragma unroll
            for (int it = 0; it < 2; ++it) {
                const float* src = A + (size_t)arow[it]*512 + kn + sk[it];
                fa[it][0] = *(const float4*)src;
                fa[it][1] = *(const float4*)(src + 4);
                fb[it] = *(const short8*)(Bbf + (size_t)(col0 + sr[it])*512 + kn + sk[it]);
            }
        }
        short8 af[4], bfr[4];
#pragma unroll
        for (int mm = 0; mm < 4; ++mm)
            af[mm] = *(const short8*)(&Asl[(wm*64 + mm*16 + lrow)*40 + quad*8]);
#pragma unroll
        for (int nn = 0; nn < 4; ++nn)
            bfr[nn] = *(const short8*)(&Bsl[(wn*64 + nn*16 + lrow)*40 + quad*8]);
#pragma unroll
        for (int mm = 0; mm < 4; ++mm)
#pragma unroll
            for (int nn = 0; nn < 4; ++nn)
                acc[mm][nn] = __builtin_amdgcn_mfma_f32_16x16x32_bf16(
                    af[mm], bfr[nn], acc[mm][nn], 0, 0, 0);
        __syncthreads();
    }

#pragma unroll
    for (int mm = 0; mm < 4; ++mm) {
        int rbase = row0 + wm*64 + mm*16 + quad*4;
#pragma unroll
        for (int nn = 0; nn < 4; ++nn) {
            int c = col0 + wn*64 + nn*16 + lrow;
            int off = (c & 63)*8 + (c >> 6);     // permuted layout
#pragma unroll
            for (int r = 0; r < 4; ++r) {
                int grow = rbase + r;
                if (grow < M)
                    H1p[(size_t)grow*512 + off] = f2bf(acc[mm][nn][r]);
            }
        }
    }
}

// ---------------------------------------------------------------------------
// Layer-2 MFMA GEMM: H2p[M,64] = hcatb[M,512] @ Woutb^T (cols 40..63 zero).
__global__ __launch_bounds__(256) void mfma_gemm2(const unsigned short* __restrict__ Abf,
                                                  const unsigned short* __restrict__ Bbf,
                                                  float* __restrict__ H2p, int M) {
    __shared__ short Asl[256*40];
    __shared__ short Bsl[64*40];
    int tid  = threadIdx.x;
    int wid  = tid >> 6, lane = tid & 63;
    int lrow = lane & 15, quad = lane >> 4;
    int row0 = blockIdx.x * 256;

    floatx4 acc[4][4];
#pragma unroll
    for (int mm = 0; mm < 4; mm++)
#pragma unroll
        for (int nn = 0; nn < 4; nn++) acc[mm][nn] = (floatx4){0.f,0.f,0.f,0.f};

    for (int k0 = 0; k0 < 512; k0 += 32) {
#pragma unroll
        for (int it = 0; it < 4; ++it) {
            int q  = tid + it*256;
            int r  = q >> 2, kk = (q & 3) * 8;
            int ar = row0 + r; ar = ar < M ? ar : M - 1;
            *(short8*)(&Asl[r*40 + kk]) =
                *(const short8*)(Abf + (size_t)ar*512 + k0 + kk);
        }
        {
            int r = tid >> 2, kk = (tid & 3) * 8;
            *(short8*)(&Bsl[r*40 + kk]) =
                *(const short8*)(Bbf + (size_t)r*512 + k0 + kk);
        }
        __syncthreads();
        short8 af[4], bfr[4];
#pragma unroll
        for (int mm = 0; mm < 4; ++mm)
            af[mm] = *(const short8*)(&Asl[(wid*64 + mm*16 + lrow)*40 + quad*8]);
#pragma unroll
        for (int nn = 0; nn < 4; ++nn)
            bfr[nn] = *(const short8*)(&Bsl[(nn*16 + lrow)*40 + quad*8]);
#pragma unroll
        for (int mm = 0; mm < 4; ++mm)
#pragma unroll
            for (int nn = 0; nn < 4; ++nn)
                acc[mm][nn] = __builtin_amdgcn_mfma_f32_16x16x32_bf16(
                    af[mm], bfr[nn], acc[mm][nn], 0, 0, 0);
        __syncthreads();
    }

#pragma unroll
    for (int mm = 0; mm < 4; ++mm) {
        int rbase = row0 + wid*64 + mm*16 + quad*4;
#pragma unroll
        for (int nn = 0; nn < 4; ++nn) {
            int c = nn*16 + lrow;
#pragma unroll
            for (int r = 0; r < 4; ++r) {
                int grow = rbase + r;
                if (grow < M)
                    H2p[(size_t)grow*64 + c] = acc[mm][nn][r];
            }
        }
    }
}

// ---------------------------------------------------------------------------
// Attention dots from PERMUTED H1p. One wave per node; lane = feature d.
__global__ __launch_bounds__(256) void dots1(const unsigned short* __restrict__ H1p,
                                             const float* __restrict__ a_heads,
                                             float* __restrict__ srcdot,
                                             float* __restrict__ dstdot) {
    int wave = (blockIdx.x*256 + threadIdx.x) >> 6;
    int lane = threadIdx.x & 63;
    if (wave >= N_NODES) return;
    short8 hv = *(const short8*)(H1p + (size_t)wave*512 + lane*8);
    float s0[8], s1[8];
#pragma unroll
    for (int j = 0; j < 8; j++) {
        float h = bf2f((unsigned short)hv[j]);
        s0[j] = h * a_heads[j*128 + lane];
        s1[j] = h * a_heads[j*128 + 64 + lane];
    }
#pragma unroll
    for (int off = 32; off > 0; off >>= 1) {
#pragma unroll
        for (int j = 0; j < 8; j++) {
            s0[j] += __shfl_down(s0[j], off, 64);
            s1[j] += __shfl_down(s1[j], off, 64);
        }
    }
    if (lane == 0) {
#pragma unroll
        for (int j = 0; j < 8; j++) {
            srcdot[wave*8 + j] = s0[j];
            dstdot[wave*8 + j] = s1[j];
        }
    }
}

// ---------------------------------------------------------------------------
// CSR build
__global__ void histk(const int* __restrict__ row, int* __restrict__ deg) {
    int e = blockIdx.x*256 + threadIdx.x;
    if (e < N_EDGES) atomicAdd(&deg[row[e]], 1);
}
__global__ void scanA(const int* __restrict__ deg, int* __restrict__ row_ptr,
                      int* __restrict__ chunk_tot) {
    __shared__ int s[256];
    int t = threadIdx.x;
    int idx = blockIdx.x*256 + t;
    int v = (idx < N_NODES) ? deg[idx] : 0;
    s[t] = v;
    __syncthreads();
#pragma unroll
    for (int off = 1; off < 256; off <<= 1) {
        int x = (t >= off) ? s[t-off] : 0;
        __syncthreads();
        s[t] += x;
        __syncthreads();
    }
    if (idx < N_NODES) row_ptr[idx] = s[t] - v;
    if (t == 255) chunk_tot[blockIdx.x] = s[t];
}
__global__ void scanB(const int* __restrict__ chunk_tot, int* __restrict__ chunk_off,
                      int* __restrict__ row_ptr) {
    __shared__ int s[256];
    int t = threadIdx.x;
    int v = (t < NCHUNK) ? chunk_tot[t] : 0;
    s[t] = v;
    __syncthreads();
#pragma unroll
    for (int off = 1; off < 256; off <<= 1) {
        int x = (t >= off) ? s[t-off] : 0;
        __syncthreads();
        s[t] += x;
        __syncthreads();
    }
    if (t < NCHUNK) chunk_off[t] = s[t] - v;
    if (t == 255) row_ptr[N_NODES] = s[t];
}
__global__ void scanC(const int* __restrict__ chunk_off, int* __restrict__ row_ptr,
                      int* __restrict__ cursor) {
    int idx = blockIdx.x*256 + threadIdx.x;
    if (idx < N_NODES) {
        int rp = row_ptr[idx] + chunk_off[idx >> 8];
        row_ptr[idx] = rp;
        cursor[idx] = rp;
    }
}

// Fused CSR fill + layer-1 edge weights, stored in CSR slot order.
// (One thread per edge computes the 8 head weights ONCE — agg1 then reads
//  them via wave-uniform s_loads. Recomputing per-lane in agg1 was the
//  round-1 regression: 512 expf/edge instead of 8.)
__global__ void fillk_w1(const int* __restrict__ row, const int* __restrict__ col,
                         const float* __restrict__ srcdot, const float* __restrict__ dstdot,
                         int* __restrict__ cursor, int* __restrict__ csr_col,
                         float* __restrict__ Wcsr) {
    int e = blockIdx.x*256 + threadIdx.x;
    if (e >= N_EDGES) return;
    int r = row[e], c = col[e];
    int pos = atomicAdd(&cursor[r], 1);
    csr_col[pos] = c;
    float4 sa = *(const float4*)(srcdot + (size_t)r*8);
    float4 sb = *(const float4*)(srcdot + (size_t)r*8 + 4);
    float4 da = *(const float4*)(dstdot + (size_t)c*8);
    float4 db = *(const float4*)(dstdot + (size_t)c*8 + 4);
    float s[8] = {sa.x+da.x, sa.y+da.y, sa.z+da.z, sa.w+da.w,
                  sb.x+db.x, sb.y+db.y, sb.z+db.z, sb.w+db.w};
    float o[8];
#pragma unroll
    for (int j = 0; j < 8; j++) {
        float lr = s[j] > 0.f ? s[j] : ALPHA*s[j];
        o[j] = __expf(-lr);
    }
    *(float4*)(Wcsr + (size_t)pos*8)     = make_float4(o[0], o[1], o[2], o[3]);
    *(float4*)(Wcsr + (size_t)pos*8 + 4) = make_float4(o[4], o[5], o[6], o[7]);
}

// ---------------------------------------------------------------------------
// Layer-1 aggregation + ELU, software-pipelined.
//  * all col indices of the node preloaded into one register (colreg) -> no
//    csr_col load on the gather critical path (readlane extracts them)
//  * 2-color x 3-edge batches: batch B's 3 gathers are issued before batch A
//    is consumed, so ~6 gathers stay in flight per wave
//  * weights come precomputed from Wcsr at wave-uniform addresses (s_load),
//    so per-edge VGPR state is just the short8 gather (4 VGPR).
__global__ __launch_bounds__(256) void agg1(const unsigned short* __restrict__ H1p,
                                            const float* __restrict__ Wcsr,
                                            const int* __restrict__ row_ptr,
                                            const int* __restrict__ csr_col,
                                            unsigned short* __restrict__ hcatb) {
    int wave = (blockIdx.x*256 + threadIdx.x) >> 6;
    int lane = threadIdx.x & 63;
    if (wave >= N_NODES) return;
    int start = row_ptr[wave], end = row_ptr[wave+1];
    int deg = end - start;

    float acc0=0.f,acc1=0.f,acc2=0.f,acc3=0.f,acc4=0.f,acc5=0.f,acc6=0.f,acc7=0.f;
    float den0=0.f,den1=0.f,den2=0.f,den3=0.f,den4=0.f,den5=0.f,den6=0.f,den7=0.f;

    int colreg = 0;
    if (deg > 0) colreg = csr_col[start + (lane < deg ? lane : deg - 1)];

#define CONS1(H, W0, W1) do { \
    den0+=(W0).x; acc0=fmaf((W0).x, bf2f((unsigned short)(H)[0]), acc0); \
    den1+=(W0).y; acc1=fmaf((W0).y, bf2f((unsigned short)(H)[1]), acc1); \
    den2+=(W0).z; acc2=fmaf((W0).z, bf2f((unsigned short)(H)[2]), acc2); \
    den3+=(W0).w; acc3=fmaf((W0).w, bf2f((unsigned short)(H)[3]), acc3); \
    den4+=(W1).x; acc4=fmaf((W1).x, bf2f((unsigned short)(H)[4]), acc4); \
    den5+=(W1).y; acc5=fmaf((W1).y, bf2f((unsigned short)(H)[5]), acc5); \
    den6+=(W1).z; acc6=fmaf((W1).z, bf2f((unsigned short)(H)[6]), acc6); \
    den7+=(W1).w; acc7=fmaf((W1).w, bf2f((unsigned short)(H)[7]), acc7); \
} while(0)

#define GATH3(HS0,HS1,HS2,W0,W1,W2,W3,W4,W5,B) do { \
    int cg0_ = __builtin_amdgcn_readlane(colreg, (B)); \
    int cg1_ = __builtin_amdgcn_readlane(colreg, (B)+1); \
    int cg2_ = __builtin_amdgcn_readlane(colreg, (B)+2); \
    HS0 = *(const short8*)(H1p + (size_t)cg0_*512 + lane*8); \
    HS1 = *(const short8*)(H1p + (size_t)cg1_*512 + lane*8); \
    HS2 = *(const short8*)(H1p + (size_t)cg2_*512 + lane*8); \
    const float* wp_ = Wcsr + (size_t)(start + (B))*8; \
    W0 = *(const float4*)(wp_);      W1 = *(const float4*)(wp_ + 4); \
    W2 = *(const float4*)(wp_ + 8);  W3 = *(const float4*)(wp_ + 12); \
    W4 = *(const float4*)(wp_ + 16); W5 = *(const float4*)(wp_ + 20); \
} while(0)

#define CONS3(HS0,HS1,HS2,W0,W1,W2,W3,W4,W5) do { \
    CONS1(HS0,W0,W1); CONS1(HS1,W2,W3); CONS1(HS2,W4,W5); } while(0)

    int lim = deg < 64 ? deg : 64;
    int nb = lim / 3;
    int k = start;
    short8 ha0, ha1, ha2, hb0, hb1, hb2;
    float4 wa0, wa1, wa2, wa3, wa4, wa5;
    float4 wb0, wb1, wb2, wb3, wb4, wb5;
    if (nb > 0) {
        GATH3(ha0,ha1,ha2, wa0,wa1,wa2,wa3,wa4,wa5, 0);
        int b = 1;
        for (; b + 1 < nb; b += 2) {
            GATH3(hb0,hb1,hb2, wb0,wb1,wb2,wb3,wb4,wb5, b*3);
            CONS3(ha0,ha1,ha2, wa0,wa1,wa2,wa3,wa4,wa5);
            GATH3(ha0,ha1,ha2, wa0,wa1,wa2,wa3,wa4,wa5, (b+1)*3);
            CONS3(hb0,hb1,hb2, wb0,wb1,wb2,wb3,wb4,wb5);
        }
        if (b < nb) {
            GATH3(hb0,hb1,hb2, wb0,wb1,wb2,wb3,wb4,wb5, b*3);
            CONS3(ha0,ha1,ha2, wa0,wa1,wa2,wa3,wa4,wa5);
            CONS3(hb0,hb1,hb2, wb0,wb1,wb2,wb3,wb4,wb5);
        } else {
            CONS3(ha0,ha1,ha2, wa0,wa1,wa2,wa3,wa4,wa5);
        }
        k = start + nb*3;
    }
    for (; k < end; ++k) {
        int c_ = (k - start < 64) ? __builtin_amdgcn_readlane(colreg, k - start)
                                  : csr_col[k];
        short8 hv = *(const short8*)(H1p + (size_t)c_*512 + lane*8);
        float4 w0 = *(const float4*)(Wcsr + (size_t)k*8);
        float4 w1 = *(const float4*)(Wcsr + (size_t)k*8 + 4);
        CONS1(hv, w0, w1);
    }
#undef GATH3
#undef CONS3
#undef CONS1

    {
        float accv[8] = {acc0,acc1,acc2,acc3,acc4,acc5,acc6,acc7};
        float denv[8] = {den0,den1,den2,den3,den4,den5,den6,den7};
#pragma unroll
        for (int j = 0; j < 8; j++) {
            float o = accv[j] / (denv[j] + EPS_F);
            o = o > 0.f ? o : (__expf(o) - 1.f);   // ELU
            hcatb[(size_t)wave*HD + j*64 + lane] = f2bf(o);
        }
    }
}

// ---------------------------------------------------------------------------
// Final attention dots: one wave per node, coalesced H2p row read + shuffle
// reduce (replaces stride-64 scalar loop).
__global__ __launch_bounds__(256) void dots2(const float* __restrict__ H2p,
                                             const float* __restrict__ a_out,
                                             float* __restrict__ src2,
                                             float* __restrict__ dst2) {
    int wave = (blockIdx.x*256 + threadIdx.x) >> 6;
    int lane = threadIdx.x & 63;
    if (wave >= N_NODES) return;
    float h  = H2p[(size_t)wave*64 + lane];
    float a0 = lane < NCLASS ? a_out[lane] : 0.f;
    float a1 = lane < NCLASS ? a_out[NCLASS + lane] : 0.f;
    float s0 = h * a0, s1 = h * a1;
#pragma unroll
    for (int off = 32; off > 0; off >>= 1) {
        s0 += __shfl_down(s0, off, 64);
        s1 += __shfl_down(s1, off, 64);
    }
    if (lane == 0) { src2[wave] = s0; dst2[wave] = s1; }
}

// ---------------------------------------------------------------------------
// Final aggregation, software-pipelined (8-edge x 2-color batches;
// per-edge state is 2 floats so registers stay cheap).
__global__ __launch_bounds__(256) void agg2(const float* __restrict__ H2p,
                                            const float* __restrict__ src2,
                                            const float* __restrict__ dst2,
                                            const int* __restrict__ row_ptr,
                                            const int* __restrict__ csr_col,
                                            float* __restrict__ out) {
    int wave = (blockIdx.x*256 + threadIdx.x) >> 6;
    int lane = threadIdx.x & 63;
    if (wave >= N_NODES) return;
    int start = row_ptr[wave], end = row_ptr[wave+1];
    int deg = end - start;
    float s2i = src2[wave];
    int l = lane < NCLASS ? lane : 0;
    float acc = 0.f, den = 0.f;

    int colreg = 0;
    if (deg > 0) colreg = csr_col[start + (lane < deg ? lane : deg - 1)];

#define AG2_G1(T, H, IDX) do { \
    int cg_ = __builtin_amdgcn_readlane(colreg, (IDX)); \
    T = dst2[cg_]; \
    H = H2p[(size_t)cg_*64 + l]; \
} while(0)
#define AG2_C1(T, H) do { \
    float t_ = s2i + (T); \
    t_ = t_ > 0.f ? t_ : ALPHA*t_; \
    float w_ = __expf(-t_); \
    den += w_; acc = fmaf(w_, (H), acc); \
} while(0)
#define AG2_G8(T0,T1,T2,T3,T4,T5,T6,T7,H0,H1,H2,H3,H4,H5,H6,H7,BASE) do { \
    AG2_G1(T0,H0,(BASE));   AG2_G1(T1,H1,(BASE)+1); \
    AG2_G1(T2,H2,(BASE)+2); AG2_G1(T3,H3,(BASE)+3); \
    AG2_G1(T4,H4,(BASE)+4); AG2_G1(T5,H5,(BASE)+5); \
    AG2_G1(T6,H6,(BASE)+6); AG2_G1(T7,H7,(BASE)+7); \
} while(0)
#define AG2_C8(T0,T1,T2,T3,T4,T5,T6,T7,H0,H1,H2,H3,H4,H5,H6,H7) do { \
    AG2_C1(T0,H0); AG2_C1(T1,H1); AG2_C1(T2,H2); AG2_C1(T3,H3); \
    AG2_C1(T4,H4); AG2_C1(T5,H5); AG2_C1(T6,H6); AG2_C1(T7,H7); \
} while(0)

    int lim = deg < 64 ? deg : 64;
    int nb = lim >> 3;
    int k = start;
    float ta0,ta1,ta2,ta3,ta4,ta5,ta6,ta7, ga0,ga1,ga2,ga3,ga4,ga5,ga6,ga7;
    float tb0,tb1,tb2,tb3,tb4,tb5,tb6,tb7, gb0,gb1,gb2,gb3,gb4,gb5,gb6,gb7;
    if (nb > 0) {
        AG2_G8(ta0,ta1,ta2,ta3,ta4,ta5,ta6,ta7, ga0,ga1,ga2,ga3,ga4,ga5,ga6,ga7, 0);
        int b = 1;
        for (; b + 1 < nb; b += 2) {
            AG2_G8(tb0,tb1,tb2,tb3,tb4,tb5,tb6,tb7, gb0,gb1,gb2,gb3,gb4,gb5,gb6,gb7, b*8);
            AG2_C8(ta0,ta1,ta2,ta3,ta4,ta5,ta6,ta7, ga0,ga1,ga2,ga3,ga4,ga5,ga6,ga7);
            AG2_G8(ta0,ta1,ta2,ta3,ta4,ta5,ta6,ta7, ga0,ga1,ga2,ga3,ga4,ga5,ga6,ga7, (b+1)*8);
            AG2_C8(tb0,tb1,tb2,tb3,tb4,tb5,tb6,tb7, gb0,gb1,gb2,gb3,gb4,gb5,gb6,gb7);
        }
        if (b < nb) {
            AG2_G8(tb0,tb1,tb2,tb3,tb4,tb5,tb6,tb7, gb0,gb1,gb2,gb3,gb4,gb5,gb6,gb7, b*8);
            AG2_C8(ta0,ta1,ta2,ta3,ta4,ta5,ta6,ta7, ga0,ga1,ga2,ga3,ga4,ga5,ga6,ga7);
            AG2_C8(tb0,tb1,tb2,tb3,tb4,tb5,tb6,tb7, gb0,gb1,gb2,gb3,gb4,gb5,gb6,gb7);
        } else {
            AG2_C8(ta0,ta1,ta2,ta3,ta4,ta5,ta6,ta7, ga0,ga1,ga2,ga3,ga4,ga5,ga6,ga7);
        }
        k = start + nb*8;
    }
    for (; k < end; ++k) {
        int c_ = (k - start < 64) ? __builtin_amdgcn_readlane(colreg, k - start)
                                  : csr_col[k];
        float t = dst2[c_];
        float h = H2p[(size_t)c_*64 + l];
        AG2_C1(t, h);
    }
#undef AG2_G1
#undef AG2_C1
#undef AG2_G8
#undef AG2_C8

    if (lane < NCLASS)
        out[(size_t)wave*NCLASS + lane] = acc / (den + EPS_F);
}

// ---------------------------------------------------------------------------
extern "C" void kernel_launch(void* const* d_in, const int* in_sizes, int n_in,
                              void* d_out, int out_size, void* d_ws, size_t ws_size,
                              hipStream_t stream) {
    const float* x       = (const float*)d_in[0];
    const float* W_heads = (const float*)d_in[1];
    const float* a_heads = (const float*)d_in[2];
    const float* W_out   = (const float*)d_in[3];
    const float* a_out   = (const float*)d_in[4];
    const int*   ei      = (const int*)d_in[5];
    const int*   row     = ei;
    const int*   col     = ei + N_EDGES;
    float* out = (float*)d_out;

    char* ws = (char*)d_ws;
    size_t off = 0;
    auto alloc = [&](size_t bytes) {
        char* p = ws + off;
        off = (off + bytes + 255) & ~(size_t)255;
        return p;
    };
    unsigned short* Wrb   = (unsigned short*)alloc((size_t)512*512*2);
    unsigned short* Wob   = (unsigned short*)alloc((size_t)64*512*2);
    unsigned short* H1p   = (unsigned short*)alloc((size_t)N_NODES*HD*2);
    unsigned short* hcatb = (unsigned short*)alloc((size_t)N_NODES*HD*2);
    float* srcdot  = (float*)alloc((size_t)N_NODES*NHEADS*4);
    float* dstdot  = (float*)alloc((size_t)N_NODES*NHEADS*4);
    float* Wcsr    = (float*)alloc((size_t)N_EDGES*NHEADS*4);
    int*   deg     = (int*)alloc((size_t)N_NODES*4);
    int*   row_ptr = (int*)alloc((size_t)(N_NODES+1)*4);
    int*   cursor  = (int*)alloc((size_t)N_NODES*4);
    int*   ctot    = (int*)alloc(256*4);
    int*   coff    = (int*)alloc(256*4);
    int*   csr_col = (int*)alloc((size_t)N_EDGES*4);
    float* H2p     = (float*)alloc((size_t)N_NODES*64*4);
    float* src2    = (float*)alloc((size_t)N_NODES*4);
    float* dst2    = (float*)alloc((size_t)N_NODES*4);
    (void)ws_size;

    const int EB = (N_EDGES + 255)/256;
    const int WB = (N_NODES*64 + 255)/256;   // wave-per-node grids

    // Layer 1
    prep<<<(512*512 + 255)/256, 256, 0, stream>>>(W_heads, Wrb, W_out, Wob, deg);
    {
        int rtiles = (N_NODES + 127)/128;            // 391
        int nblk = ((rtiles + 7)/8) * 32;            // 1568
        mfma_gemm1<<<nblk, 256, 0, stream>>>(x, Wrb, H1p, N_NODES);
    }
    dots1<<<WB, 256, 0, stream>>>(H1p, a_heads, srcdot, dstdot);

    // CSR build + fused layer-1 edge weights
    histk<<<EB, 256, 0, stream>>>(row, deg);
    scanA<<<NCHUNK, 256, 0, stream>>>(deg, row_ptr, ctot);
    scanB<<<1, 256, 0, stream>>>(ctot, coff, row_ptr);
    scanC<<<NCHUNK, 256, 0, stream>>>(coff, row_ptr, cursor);
    fillk_w1<<<EB, 256, 0, stream>>>(row, col, srcdot, dstdot, cursor,
                                     csr_col, Wcsr);

    agg1<<<WB, 256, 0, stream>>>(H1p, Wcsr, row_ptr, csr_col, hcatb);

    // Layer 2
    mfma_gemm2<<<(N_NODES + 255)/256, 256, 0, stream>>>(hcatb, Wob, H2p, N_NODES);
    dots2<<<WB, 256, 0, stream>>>(H2p, a_out, src2, dst2);
    agg2<<<WB, 256, 0, stream>>>(H2p, src2, dst2, row_ptr, csr_col, out);
}

// Round 3
// 510.135 us; speedup vs baseline: 1.1090x; 1.0914x over previous
//
#include <hip/hip_runtime.h>
#include <hip/hip_bf16.h>

#define N_NODES 50000
#define N_EDGES 800000
#define NFEAT   512
#define NHID    64
#define NHEADS  8
#define NCLASS  40
#define HD      (NHEADS*NHID)   // 512
#define ALPHA   0.2f
#define EPS_F   1e-16f
#define NCHUNK  ((N_NODES + 255)/256)   // 196

typedef __attribute__((ext_vector_type(8))) short short8;
typedef __attribute__((ext_vector_type(4))) float floatx4;

__device__ __forceinline__ float bf2f(unsigned short u) {
    union { unsigned int i; float f; } v; v.i = ((unsigned int)u) << 16; return v.f;
}
__device__ __forceinline__ unsigned short f2bf(float f) {
    union { __hip_bfloat16 h; unsigned short u; } cv;
    cv.h = __float2bfloat16(f);
    return cv.u;
}

// ---------------------------------------------------------------------------
// Fused prep: repack W_heads -> Wrb (B^T bf16), W_out -> Wob (padded B^T bf16),
// zero deg. One launch instead of three.
__global__ void prep(const float* __restrict__ Wh, unsigned short* __restrict__ Wrb,
                     const float* __restrict__ Wo, unsigned short* __restrict__ Wob,
                     int* __restrict__ deg) {
    int idx = blockIdx.x*256 + threadIdx.x;      // < 512*512
    if (idx >= 512*512) return;
    if (idx < N_NODES) deg[idx] = 0;
    {
        int n = idx >> 9, k = idx & 511;
        int hd = n >> 6, d = n & 63;
        Wrb[idx] = f2bf(Wh[(size_t)hd*NFEAT*NHID + (size_t)k*NHID + d]);
    }
    if (idx < 64*512) {
        int n = idx >> 9, k = idx & 511;
        float v = (n < NCLASS) ? Wo[(size_t)k*NCLASS + n] : 0.f;
        Wob[idx] = f2bf(v);
    }
}

// ---------------------------------------------------------------------------
// Layer-1 MFMA GEMM with FUSED attention dots.
// 256 threads, 128x128 tile, XCD swizzle, fused fp32->bf16 A staging,
// register-prefetch pipeline. Each block owns cols [cb*128, cb*128+128) =
// heads {2cb, 2cb+1} fully, so it computes COMPLETE srcdot/dstdot for its
// 128 rows x 2 heads from the f32 accumulators (in-lane dot over nn +
// 16-lane shfl reduce) — removes the dots1 kernel and its 50MB H1p re-read.
// Output permuted: H1p[row*512 + d*8 + hd] (col c = hd*64+d).
__global__ __launch_bounds__(256) void mfma_gemm1(const float* __restrict__ A,
                                                  const unsigned short* __restrict__ Bbf,
                                                  const float* __restrict__ a_heads,
                                                  unsigned short* __restrict__ H1p,
                                                  float* __restrict__ srcdot,
                                                  float* __restrict__ dstdot, int M) {
    int id = blockIdx.x;
    int rb = (id >> 5)*8 + (id & 7);     // row tile (XCD swizzle)
    int cb = (id >> 3) & 3;
    int row0 = rb * 128, col0 = cb * 128;
    if (row0 >= M) return;

    __shared__ short Asl[128*40];
    __shared__ short Bsl[128*40];
    int tid  = threadIdx.x;
    int wid  = tid >> 6, lane = tid & 63;
    int lrow = lane & 15, quad = lane >> 4;
    int wm = wid & 1, wn = wid >> 1;

    int sr[2], sk[2];
#pragma unroll
    for (int it = 0; it < 2; ++it) {
        int q = tid + it*256;
        sr[it] = q >> 2; sk[it] = (q & 3) * 8;
    }
    int arow[2];
#pragma unroll
    for (int it = 0; it < 2; ++it) {
        int ar = row0 + sr[it];
        arow[it] = ar < M ? ar : M - 1;
    }

    floatx4 acc[4][4];
#pragma unroll
    for (int mm = 0; mm < 4; mm++)
#pragma unroll
        for (int nn = 0; nn < 4; nn++) acc[mm][nn] = (floatx4){0.f,0.f,0.f,0.f};

    float4 fa[2][2];
    short8 fb[2];
#pragma unroll
    for (int it = 0; it < 2; ++it) {
        const float* src = A + (size_t)arow[it]*512 + sk[it];
        fa[it][0] = *(const float4*)src;
        fa[it][1] = *(const float4*)(src + 4);
        fb[it] = *(const short8*)(Bbf + (size_t)(col0 + sr[it])*512 + sk[it]);
    }

    for (int k0 = 0; k0 < 512; k0 += 32) {
#pragma unroll
        for (int it = 0; it < 2; ++it) {
            short8 h;
            h[0] = (short)f2bf(fa[it][0].x); h[1] = (short)f2bf(fa[it][0].y);
            h[2] = (short)f2bf(fa[it][0].z); h[3] = (short)f2bf(fa[it][0].w);
            h[4] = (short)f2bf(fa[it][1].x); h[5] = (short)f2bf(fa[it][1].y);
            h[6] = (short)f2bf(fa[it][1].z); h[7] = (short)f2bf(fa[it][1].w);
            *(short8*)(&Asl[sr[it]*40 + sk[it]]) = h;
            *(short8*)(&Bsl[sr[it]*40 + sk[it]]) = fb[it];
        }
        __syncthreads();
        if (k0 + 32 < 512) {
            int kn = k0 + 32;
#pragma unroll
            for (int it = 0; it < 2; ++it) {
                const float* src = A + (size_t)arow[it]*512 + kn + sk[it];
                fa[it][0] = *(const float4*)src;
                fa[it][1] = *(const float4*)(src + 4);
                fb[it] = *(const short8*)(Bbf + (size_t)(col0 + sr[it])*512 + kn + sk[it]);
            }
        }
        short8 af[4], bfr[4];
#pragma unroll
        for (int mm = 0; mm < 4; ++mm)
            af[mm] = *(const short8*)(&Asl[(wm*64 + mm*16 + lrow)*40 + quad*8]);
#pragma unroll
        for (int nn = 0; nn < 4; ++nn)
            bfr[nn] = *(const short8*)(&Bsl[(wn*64 + nn*16 + lrow)*40 + quad*8]);
#pragma unroll
        for (int mm = 0; mm < 4; ++mm)
#pragma unroll
            for (int nn = 0; nn < 4; ++nn)
                acc[mm][nn] = __builtin_amdgcn_mfma_f32_16x16x32_bf16(
                    af[mm], bfr[nn], acc[mm][nn], 0, 0, 0);
        __syncthreads();
    }

    // ---- fused attention dots for this block's head = cb*2 + wn ----
    {
        int head = (col0 >> 6) + wn;     // cb*2 + wn
        float a0v[4], a1v[4];
#pragma unroll
        for (int nn = 0; nn < 4; ++nn) {
            a0v[nn] = a_heads[head*128 + nn*16 + lrow];
            a1v[nn] = a_heads[head*128 + 64 + nn*16 + lrow];
        }
#pragma unroll
        for (int mm = 0; mm < 4; ++mm) {
#pragma unroll
            for (int r = 0; r < 4; ++r) {
                float s0 = 0.f, s1 = 0.f;
#pragma unroll
                for (int nn = 0; nn < 4; ++nn) {
                    float v = acc[mm][nn][r];
                    s0 = fmaf(v, a0v[nn], s0);
                    s1 = fmaf(v, a1v[nn], s1);
                }
#pragma unroll
                for (int off = 1; off < 16; off <<= 1) {
                    s0 += __shfl_xor(s0, off, 64);
                    s1 += __shfl_xor(s1, off, 64);
                }
                int grow = row0 + wm*64 + mm*16 + quad*4 + r;
                if (lrow == 0 && grow < M) {
                    srcdot[(size_t)grow*8 + head] = s0;
                    dstdot[(size_t)grow*8 + head] = s1;
                }
            }
        }
    }

#pragma unroll
    for (int mm = 0; mm < 4; ++mm) {
        int rbase = row0 + wm*64 + mm*16 + quad*4;
#pragma unroll
        for (int nn = 0; nn < 4; ++nn) {
            int c = col0 + wn*64 + nn*16 + lrow;
            int off = (c & 63)*8 + (c >> 6);     // permuted layout
#pragma unroll
            for (int r = 0; r < 4; ++r) {
                int grow = rbase + r;
                if (grow < M)
                    H1p[(size_t)grow*512 + off] = f2bf(acc[mm][nn][r]);
            }
        }
    }
}

// ---------------------------------------------------------------------------
// Layer-2 MFMA GEMM with FUSED final dots: H2p[M,64] = hcatb[M,512] @ Woutb^T
// (cols 40..63 zero). Each block owns all 64 cols, so it computes complete
// src2/dst2 for its 256 rows from the f32 accumulators — removes dots2.
__global__ __launch_bounds__(256) void mfma_gemm2(const unsigned short* __restrict__ Abf,
                                                  const unsigned short* __restrict__ Bbf,
                                                  const float* __restrict__ a_out,
                                                  float* __restrict__ H2p,
                                                  float* __restrict__ src2,
                                                  float* __restrict__ dst2, int M) {
    __shared__ short Asl[256*40];
    __shared__ short Bsl[64*40];
    int tid  = threadIdx.x;
    int wid  = tid >> 6, lane = tid & 63;
    int lrow = lane & 15, quad = lane >> 4;
    int row0 = blockIdx.x * 256;

    floatx4 acc[4][4];
#pragma unroll
    for (int mm = 0; mm < 4; mm++)
#pragma unroll
        for (int nn = 0; nn < 4; nn++) acc[mm][nn] = (floatx4){0.f,0.f,0.f,0.f};

    for (int k0 = 0; k0 < 512; k0 += 32) {
#pragma unroll
        for (int it = 0; it < 4; ++it) {
            int q  = tid + it*256;
            int r  = q >> 2, kk = (q & 3) * 8;
            int ar = row0 + r; ar = ar < M ? ar : M - 1;
            *(short8*)(&Asl[r*40 + kk]) =
                *(const short8*)(Abf + (size_t)ar*512 + k0 + kk);
        }
        {
            int r = tid >> 2, kk = (tid & 3) * 8;
            *(short8*)(&Bsl[r*40 + kk]) =
                *(const short8*)(Bbf + (size_t)r*512 + k0 + kk);
        }
        __syncthreads();
        short8 af[4], bfr[4];
#pragma unroll
        for (int mm = 0; mm < 4; ++mm)
            af[mm] = *(const short8*)(&Asl[(wid*64 + mm*16 + lrow)*40 + quad*8]);
#pragma unroll
        for (int nn = 0; nn < 4; ++nn)
            bfr[nn] = *(const short8*)(&Bsl[(nn*16 + lrow)*40 + quad*8]);
#pragma unroll
        for (int mm = 0; mm < 4; ++mm)
#pragma unroll
            for (int nn = 0; nn < 4; ++nn)
                acc[mm][nn] = __builtin_amdgcn_mfma_f32_16x16x32_bf16(
                    af[mm], bfr[nn], acc[mm][nn], 0, 0, 0);
        __syncthreads();
    }

    // ---- fused final attention dots (cols 40..63 of acc are exactly 0) ----
    {
        float a0v[4], a1v[4];
#pragma unroll
        for (int nn = 0; nn < 4; ++nn) {
            int c = nn*16 + lrow;
            a0v[nn] = c < NCLASS ? a_out[c] : 0.f;
            a1v[nn] = c < NCLASS ? a_out[NCLASS + c] : 0.f;
        }
#pragma unroll
        for (int mm = 0; mm < 4; ++mm) {
#pragma unroll
            for (int r = 0; r < 4; ++r) {
                float s0 = 0.f, s1 = 0.f;
#pragma unroll
                for (int nn = 0; nn < 4; ++nn) {
                    float v = acc[mm][nn][r];
                    s0 = fmaf(v, a0v[nn], s0);
                    s1 = fmaf(v, a1v[nn], s1);
                }
#pragma unroll
                for (int off = 1; off < 16; off <<= 1) {
                    s0 += __shfl_xor(s0, off, 64);
                    s1 += __shfl_xor(s1, off, 64);
                }
                int grow = row0 + wid*64 + mm*16 + quad*4 + r;
                if (lrow == 0 && grow < M) {
                    src2[grow] = s0;
                    dst2[grow] = s1;
                }
            }
        }
    }

#pragma unroll
    for (int mm = 0; mm < 4; ++mm) {
        int rbase = row0 + wid*64 + mm*16 + quad*4;
#pragma unroll
        for (int nn = 0; nn < 4; ++nn) {
            int c = nn*16 + lrow;
#pragma unroll
            for (int r = 0; r < 4; ++r) {
                int grow = rbase + r;
                if (grow < M)
                    H2p[(size_t)grow*64 + c] = acc[mm][nn][r];
            }
        }
    }
}

// ---------------------------------------------------------------------------
// CSR build
__global__ void histk(const int* __restrict__ row, int* __restrict__ deg) {
    int e = blockIdx.x*256 + threadIdx.x;
    if (e < N_EDGES) atomicAdd(&deg[row[e]], 1);
}
__global__ void scanA(const int* __restrict__ deg, int* __restrict__ row_ptr,
                      int* __restrict__ chunk_tot) {
    __shared__ int s[256];
    int t = threadIdx.x;
    int idx = blockIdx.x*256 + t;
    int v = (idx < N_NODES) ? deg[idx] : 0;
    s[t] = v;
    __syncthreads();
#pragma unroll
    for (int off = 1; off < 256; off <<= 1) {
        int x = (t >= off) ? s[t-off] : 0;
        __syncthreads();
        s[t] += x;
        __syncthreads();
    }
    if (idx < N_NODES) row_ptr[idx] = s[t] - v;
    if (t == 255) chunk_tot[blockIdx.x] = s[t];
}
__global__ void scanB(const int* __restrict__ chunk_tot, int* __restrict__ chunk_off,
                      int* __restrict__ row_ptr) {
    __shared__ int s[256];
    int t = threadIdx.x;
    int v = (t < NCHUNK) ? chunk_tot[t] : 0;
    s[t] = v;
    __syncthreads();
#pragma unroll
    for (int off = 1; off < 256; off <<= 1) {
        int x = (t >= off) ? s[t-off] : 0;
        __syncthreads();
        s[t] += x;
        __syncthreads();
    }
    if (t < NCHUNK) chunk_off[t] = s[t] - v;
    if (t == 255) row_ptr[N_NODES] = s[t];
}
__global__ void scanC(const int* __restrict__ chunk_off, int* __restrict__ row_ptr,
                      int* __restrict__ cursor) {
    int idx = blockIdx.x*256 + threadIdx.x;
    if (idx < N_NODES) {
        int rp = row_ptr[idx] + chunk_off[idx >> 8];
        row_ptr[idx] = rp;
        cursor[idx] = rp;
    }
}

// Fused CSR fill + layer-1 edge weights, stored in CSR slot order.
__global__ void fillk_w1(const int* __restrict__ row, const int* __restrict__ col,
                         const float* __restrict__ srcdot, const float* __restrict__ dstdot,
                         int* __restrict__ cursor, int* __restrict__ csr_col,
                         float* __restrict__ Wcsr) {
    int e = blockIdx.x*256 + threadIdx.x;
    if (e >= N_EDGES) return;
    int r = row[e], c = col[e];
    int pos = atomicAdd(&cursor[r], 1);
    csr_col[pos] = c;
    float4 sa = *(const float4*)(srcdot + (size_t)r*8);
    float4 sb = *(const float4*)(srcdot + (size_t)r*8 + 4);
    float4 da = *(const float4*)(dstdot + (size_t)c*8);
    float4 db = *(const float4*)(dstdot + (size_t)c*8 + 4);
    float s[8] = {sa.x+da.x, sa.y+da.y, sa.z+da.z, sa.w+da.w,
                  sb.x+db.x, sb.y+db.y, sb.z+db.z, sb.w+db.w};
    float o[8];
#pragma unroll
    for (int j = 0; j < 8; j++) {
        float lr = s[j] > 0.f ? s[j] : ALPHA*s[j];
        o[j] = __expf(-lr);
    }
    *(float4*)(Wcsr + (size_t)pos*8)     = make_float4(o[0], o[1], o[2], o[3]);
    *(float4*)(Wcsr + (size_t)pos*8 + 4) = make_float4(o[4], o[5], o[6], o[7]);
}

// ---------------------------------------------------------------------------
// Layer-1 aggregation + ELU. Wave per node; ONE 16-B gather per edge per lane;
// 4-edge unroll keeps 4 gathers in flight. (Round-0 form: best measured —
// deeper pipelining/readlane was neutral: agg1 is L3-fabric-fetch-bound,
// FETCH ~389MB vs ~346MB structural floor.)
__global__ __launch_bounds__(256) void agg1(const unsigned short* __restrict__ H1p,
                                            const float* __restrict__ Wcsr,
                                            const int* __restrict__ row_ptr,
                                            const int* __restrict__ csr_col,
                                            unsigned short* __restrict__ hcatb) {
    int wave = (blockIdx.x*256 + threadIdx.x) >> 6;
    int lane = threadIdx.x & 63;
    if (wave >= N_NODES) return;
    int start = row_ptr[wave], end = row_ptr[wave+1];
    float acc[8], den[8];
#pragma unroll
    for (int j = 0; j < 8; j++) { acc[j] = 0.f; den[j] = 0.f; }

    int k = start;
    for (; k + 4 <= end; k += 4) {
        int c0 = csr_col[k],   c1 = csr_col[k+1];
        int c2 = csr_col[k+2], c3 = csr_col[k+3];
        short8 hv0 = *(const short8*)(H1p + (size_t)c0*512 + lane*8);
        short8 hv1 = *(const short8*)(H1p + (size_t)c1*512 + lane*8);
        short8 hv2 = *(const short8*)(H1p + (size_t)c2*512 + lane*8);
        short8 hv3 = *(const short8*)(H1p + (size_t)c3*512 + lane*8);
        float4 wv[8];
#pragma unroll
        for (int q = 0; q < 8; q++)
            wv[q] = *(const float4*)(Wcsr + (size_t)k*8 + q*4);
        const float* w0 = (const float*)&wv[0];
        const float* w1 = (const float*)&wv[2];
        const float* w2 = (const float*)&wv[4];
        const float* w3 = (const float*)&wv[6];
#pragma unroll
        for (int j = 0; j < 8; j++) {
            den[j] += (w0[j] + w1[j]) + (w2[j] + w3[j]);
            acc[j] = fmaf(w0[j], bf2f((unsigned short)hv0[j]), acc[j]);
            acc[j] = fmaf(w1[j], bf2f((unsigned short)hv1[j]), acc[j]);
            acc[j] = fmaf(w2[j], bf2f((unsigned short)hv2[j]), acc[j]);
            acc[j] = fmaf(w3[j], bf2f((unsigned short)hv3[j]), acc[j]);
        }
    }
    for (; k < end; ++k) {
        int c = csr_col[k];
        float4 wa = *(const float4*)(Wcsr + (size_t)k*8);
        float4 wb = *(const float4*)(Wcsr + (size_t)k*8 + 4);
        short8 hv = *(const short8*)(H1p + (size_t)c*512 + lane*8);
        float w[8] = {wa.x, wa.y, wa.z, wa.w, wb.x, wb.y, wb.z, wb.w};
#pragma unroll
        for (int j = 0; j < 8; j++) {
            den[j] += w[j];
            acc[j] = fmaf(w[j], bf2f((unsigned short)hv[j]), acc[j]);
        }
    }
#pragma unroll
    for (int j = 0; j < 8; j++) {
        float o = acc[j] / (den[j] + EPS_F);
        o = o > 0.f ? o : (__expf(o) - 1.f);   // ELU
        hcatb[(size_t)wave*HD + j*64 + lane] = f2bf(o);
    }
}

// ---------------------------------------------------------------------------
// Final aggregation, software-pipelined (8-edge x 2-color batches;
// per-edge state is 2 floats so registers stay cheap).
__global__ __launch_bounds__(256) void agg2(const float* __restrict__ H2p,
                                            const float* __restrict__ src2,
                                            const float* __restrict__ dst2,
                                            const int* __restrict__ row_ptr,
                                            const int* __restrict__ csr_col,
                                            float* __restrict__ out) {
    int wave = (blockIdx.x*256 + threadIdx.x) >> 6;
    int lane = threadIdx.x & 63;
    if (wave >= N_NODES) return;
    int start = row_ptr[wave], end = row_ptr[wave+1];
    int deg = end - start;
    float s2i = src2[wave];
    int l = lane < NCLASS ? lane : 0;
    float acc = 0.f, den = 0.f;

    int colreg = 0;
    if (deg > 0) colreg = csr_col[start + (lane < deg ? lane : deg - 1)];

#define AG2_G1(T, H, IDX) do { \
    int cg_ = __builtin_amdgcn_readlane(colreg, (IDX)); \
    T = dst2[cg_]; \
    H = H2p[(size_t)cg_*64 + l]; \
} while(0)
#define AG2_C1(T, H) do { \
    float t_ = s2i + (T); \
    t_ = t_ > 0.f ? t_ : ALPHA*t_; \
    float w_ = __expf(-t_); \
    den += w_; acc = fmaf(w_, (H), acc); \
} while(0)
#define AG2_G8(T0,T1,T2,T3,T4,T5,T6,T7,H0,H1,H2,H3,H4,H5,H6,H7,BASE) do { \
    AG2_G1(T0,H0,(BASE));   AG2_G1(T1,H1,(BASE)+1); \
    AG2_G1(T2,H2,(BASE)+2); AG2_G1(T3,H3,(BASE)+3); \
    AG2_G1(T4,H4,(BASE)+4); AG2_G1(T5,H5,(BASE)+5); \
    AG2_G1(T6,H6,(BASE)+6); AG2_G1(T7,H7,(BASE)+7); \
} while(0)
#define AG2_C8(T0,T1,T2,T3,T4,T5,T6,T7,H0,H1,H2,H3,H4,H5,H6,H7) do { \
    AG2_C1(T0,H0); AG2_C1(T1,H1); AG2_C1(T2,H2); AG2_C1(T3,H3); \
    AG2_C1(T4,H4); AG2_C1(T5,H5); AG2_C1(T6,H6); AG2_C1(T7,H7); \
} while(0)

    int lim = deg < 64 ? deg : 64;
    int nb = lim >> 3;
    int k = start;
    float ta0,ta1,ta2,ta3,ta4,ta5,ta6,ta7, ga0,ga1,ga2,ga3,ga4,ga5,ga6,ga7;
    float tb0,tb1,tb2,tb3,tb4,tb5,tb6,tb7, gb0,gb1,gb2,gb3,gb4,gb5,gb6,gb7;
    if (nb > 0) {
        AG2_G8(ta0,ta1,ta2,ta3,ta4,ta5,ta6,ta7, ga0,ga1,ga2,ga3,ga4,ga5,ga6,ga7, 0);
        int b = 1;
        for (; b + 1 < nb; b += 2) {
            AG2_G8(tb0,tb1,tb2,tb3,tb4,tb5,tb6,tb7, gb0,gb1,gb2,gb3,gb4,gb5,gb6,gb7, b*8);
            AG2_C8(ta0,ta1,ta2,ta3,ta4,ta5,ta6,ta7, ga0,ga1,ga2,ga3,ga4,ga5,ga6,ga7);
            AG2_G8(ta0,ta1,ta2,ta3,ta4,ta5,ta6,ta7, ga0,ga1,ga2,ga3,ga4,ga5,ga6,ga7, (b+1)*8);
            AG2_C8(tb0,tb1,tb2,tb3,tb4,tb5,tb6,tb7, gb0,gb1,gb2,gb3,gb4,gb5,gb6,gb7);
        }
        if (b < nb) {
            AG2_G8(tb0,tb1,tb2,tb3,tb4,tb5,tb6,tb7, gb0,gb1,gb2,gb3,gb4,gb5,gb6,gb7, b*8);
            AG2_C8(ta0,ta1,ta2,ta3,ta4,ta5,ta6,ta7, ga0,ga1,ga2,ga3,ga4,ga5,ga6,ga7);
            AG2_C8(tb0,tb1,tb2,tb3,tb4,tb5,tb6,tb7, gb0,gb1,gb2,gb3,gb4,gb5,gb6,gb7);
        } else {
            AG2_C8(ta0,ta1,ta2,ta3,ta4,ta5,ta6,ta7, ga0,ga1,ga2,ga3,ga4,ga5,ga6,ga7);
        }
        k = start + nb*8;
    }
    for (; k < end; ++k) {
        int c_ = (k - start < 64) ? __builtin_amdgcn_readlane(colreg, k - start)
                                  : csr_col[k];
        float t = dst2[c_];
        float h = H2p[(size_t)c_*64 + l];
        AG2_C1(t, h);
    }
#undef AG2_G1
#undef AG2_C1
#undef AG2_G8
#undef AG2_C8

    if (lane < NCLASS)
        out[(size_t)wave*NCLASS + lane] = acc / (den + EPS_F);
}

// ---------------------------------------------------------------------------
extern "C" void kernel_launch(void* const* d_in, const int* in_sizes, int n_in,
                              void* d_out, int out_size, void* d_ws, size_t ws_size,
                              hipStream_t stream) {
    const float* x       = (const float*)d_in[0];
    const float* W_heads = (const float*)d_in[1];
    const float* a_heads = (const float*)d_in[2];
    const float* W_out   = (const float*)d_in[3];
    const float* a_out   = (const float*)d_in[4];
    const int*   ei      = (const int*)d_in[5];
    const int*   row     = ei;
    const int*   col     = ei + N_EDGES;
    float* out = (float*)d_out;

    char* ws = (char*)d_ws;
    size_t off = 0;
    auto alloc = [&](size_t bytes) {
        char* p = ws + off;
        off = (off + bytes + 255) & ~(size_t)255;
        return p;
    };
    unsigned short* Wrb   = (unsigned short*)alloc((size_t)512*512*2);
    unsigned short* Wob   = (unsigned short*)alloc((size_t)64*512*2);
    unsigned short* H1p   = (unsigned short*)alloc((size_t)N_NODES*HD*2);
    unsigned short* hcatb = (unsigned short*)alloc((size_t)N_NODES*HD*2);
    float* srcdot  = (float*)alloc((size_t)N_NODES*NHEADS*4);
    float* dstdot  = (float*)alloc((size_t)N_NODES*NHEADS*4);
    float* Wcsr    = (float*)alloc((size_t)N_EDGES*NHEADS*4);
    int*   deg     = (int*)alloc((size_t)N_NODES*4);
    int*   row_ptr = (int*)alloc((size_t)(N_NODES+1)*4);
    int*   cursor  = (int*)alloc((size_t)N_NODES*4);
    int*   ctot    = (int*)alloc(256*4);
    int*   coff    = (int*)alloc(256*4);
    int*   csr_col = (int*)alloc((size_t)N_EDGES*4);
    float* H2p     = (float*)alloc((size_t)N_NODES*64*4);
    float* src2    = (float*)alloc((size_t)N_NODES*4);
    float* dst2    = (float*)alloc((size_t)N_NODES*4);
    (void)ws_size;

    const int EB = (N_EDGES + 255)/256;
    const int WB = (N_NODES*64 + 255)/256;   // wave-per-node grids

    // Layer 1 (gemm1 also produces srcdot/dstdot)
    prep<<<(512*512 + 255)/256, 256, 0, stream>>>(W_heads, Wrb, W_out, Wob, deg);
    {
        int rtiles = (N_NODES + 127)/128;            // 391
        int nblk = ((rtiles + 7)/8) * 32;            // 1568
        mfma_gemm1<<<nblk, 256, 0, stream>>>(x, Wrb, a_heads, H1p,
                                             srcdot, dstdot, N_NODES);
    }

    // CSR build + fused layer-1 edge weights
    histk<<<EB, 256, 0, stream>>>(row, deg);
    scanA<<<NCHUNK, 256, 0, stream>>>(deg, row_ptr, ctot);
    scanB<<<1, 256, 0, stream>>>(ctot, coff, row_ptr);
    scanC<<<NCHUNK, 256, 0, stream>>>(coff, row_ptr, cursor);
    fillk_w1<<<EB, 256, 0, stream>>>(row, col, srcdot, dstdot, cursor,
                                     csr_col, Wcsr);

    agg1<<<WB, 256, 0, stream>>>(H1p, Wcsr, row_ptr, csr_col, hcatb);

    // Layer 2 (gemm2 also produces src2/dst2)
    mfma_gemm2<<<(N_NODES + 255)/256, 256, 0, stream>>>(hcatb, Wob, a_out,
                                                        H2p, src2, dst2, N_NODES);
    agg2<<<WB, 256, 0, stream>>>(H2p, src2, dst2, row_ptr, csr_col, out);
}

// Round 4
// 498.745 us; speedup vs baseline: 1.1344x; 1.0228x over previous
//
#include <hip/hip_runtime.h>
#include <hip/hip_bf16.h>

#define N_NODES 50000
#define N_EDGES 800000
#define NFEAT   512
#define NHID    64
#define NHEADS  8
#define NCLASS  40
#define HD      (NHEADS*NHID)   // 512
#define ALPHA   0.2f
#define EPS_F   1e-16f
#define NCHUNK  ((N_NODES + 255)/256)   // 196

typedef __attribute__((ext_vector_type(8))) short short8;
typedef __attribute__((ext_vector_type(4))) float floatx4;

__device__ __forceinline__ float bf2f(unsigned short u) {
    union { unsigned int i; float f; } v; v.i = ((unsigned int)u) << 16; return v.f;
}
__device__ __forceinline__ unsigned short f2bf(float f) {
    union { __hip_bfloat16 h; unsigned short u; } cv;
    cv.h = __float2bfloat16(f);
    return cv.u;
}

// ---------------------------------------------------------------------------
// Fused prep: repack W_heads -> Wrb (B^T bf16), W_out -> Wob (padded B^T bf16),
// zero deg. One launch instead of three.
__global__ void prep(const float* __restrict__ Wh, unsigned short* __restrict__ Wrb,
                     const float* __restrict__ Wo, unsigned short* __restrict__ Wob,
                     int* __restrict__ deg) {
    int idx = blockIdx.x*256 + threadIdx.x;      // < 512*512
    if (idx >= 512*512) return;
    if (idx < N_NODES) deg[idx] = 0;
    {
        int n = idx >> 9, k = idx & 511;
        int hd = n >> 6, d = n & 63;
        Wrb[idx] = f2bf(Wh[(size_t)hd*NFEAT*NHID + (size_t)k*NHID + d]);
    }
    if (idx < 64*512) {
        int n = idx >> 9, k = idx & 511;
        float v = (n < NCLASS) ? Wo[(size_t)k*NCLASS + n] : 0.f;
        Wob[idx] = f2bf(v);
    }
}

// ---------------------------------------------------------------------------
// Layer-1 MFMA GEMM with FUSED attention dots — 8-wave occupancy version.
// 512 threads, 128x128 tile, wave grid 4(m)x2(n): each wave owns 32 rows x
// 64 cols = one full head, so the dots epilogue is wave-local.
// acc[2][4] = 32 regs/thread (vs 64 before) -> ~2x waves/SIMD residency,
// which is the fix for round-3's 18.6% occupancy / 3300 cyc per K-iter.
// Output permuted: H1p[row*512 + d*8 + hd] (col c = hd*64+d).
__global__ __launch_bounds__(512, 4) void mfma_gemm1(const float* __restrict__ A,
                                                  const unsigned short* __restrict__ Bbf,
                                                  const float* __restrict__ a_heads,
                                                  unsigned short* __restrict__ H1p,
                                                  float* __restrict__ srcdot,
                                                  float* __restrict__ dstdot, int M) {
    int id = blockIdx.x;
    int rb = (id >> 5)*8 + (id & 7);     // row tile (XCD swizzle)
    int cb = (id >> 3) & 3;
    int row0 = rb * 128, col0 = cb * 128;
    if (row0 >= M) return;

    __shared__ short Asl[128*40];
    __shared__ short Bsl[128*40];
    int tid  = threadIdx.x;
    int wid  = tid >> 6, lane = tid & 63;
    int lrow = lane & 15, quad = lane >> 4;
    int wm = wid >> 1, wn = wid & 1;     // 4 x 2 wave grid

    // staging coords: one chunk per thread (512 thr x 8 elems = 128x32)
    int sr = tid >> 2, sk = (tid & 3) * 8;
    int ar = row0 + sr;
    int arow = ar < M ? ar : M - 1;

    floatx4 acc[2][4];
#pragma unroll
    for (int mm = 0; mm < 2; mm++)
#pragma unroll
        for (int nn = 0; nn < 4; nn++) acc[mm][nn] = (floatx4){0.f,0.f,0.f,0.f};

    // prefetch registers for tile k0
    float4 fa0, fa1;
    short8 fb;
    {
        const float* src = A + (size_t)arow*512 + sk;
        fa0 = *(const float4*)src;
        fa1 = *(const float4*)(src + 4);
        fb  = *(const short8*)(Bbf + (size_t)(col0 + sr)*512 + sk);
    }

    for (int k0 = 0; k0 < 512; k0 += 32) {
        {
            short8 h;
            h[0] = (short)f2bf(fa0.x); h[1] = (short)f2bf(fa0.y);
            h[2] = (short)f2bf(fa0.z); h[3] = (short)f2bf(fa0.w);
            h[4] = (short)f2bf(fa1.x); h[5] = (short)f2bf(fa1.y);
            h[6] = (short)f2bf(fa1.z); h[7] = (short)f2bf(fa1.w);
            *(short8*)(&Asl[sr*40 + sk]) = h;
            *(short8*)(&Bsl[sr*40 + sk]) = fb;
        }
        __syncthreads();
        if (k0 + 32 < 512) {
            int kn = k0 + 32;
            const float* src = A + (size_t)arow*512 + kn + sk;
            fa0 = *(const float4*)src;
            fa1 = *(const float4*)(src + 4);
            fb  = *(const short8*)(Bbf + (size_t)(col0 + sr)*512 + kn + sk);
        }
        short8 af[2], bfr[4];
#pragma unroll
        for (int mm = 0; mm < 2; ++mm)
            af[mm] = *(const short8*)(&Asl[(wm*32 + mm*16 + lrow)*40 + quad*8]);
#pragma unroll
        for (int nn = 0; nn < 4; ++nn)
            bfr[nn] = *(const short8*)(&Bsl[(wn*64 + nn*16 + lrow)*40 + quad*8]);
#pragma unroll
        for (int mm = 0; mm < 2; ++mm)
#pragma unroll
            for (int nn = 0; nn < 4; ++nn)
                acc[mm][nn] = __builtin_amdgcn_mfma_f32_16x16x32_bf16(
                    af[mm], bfr[nn], acc[mm][nn], 0, 0, 0);
        __syncthreads();
    }

    // ---- fused attention dots; this wave's head = cb*2 + wn (owns 64 cols) ----
    {
        int head = (col0 >> 6) + wn;
        float a0v[4], a1v[4];
#pragma unroll
        for (int nn = 0; nn < 4; ++nn) {
            a0v[nn] = a_heads[head*128 + nn*16 + lrow];
            a1v[nn] = a_heads[head*128 + 64 + nn*16 + lrow];
        }
#pragma unroll
        for (int mm = 0; mm < 2; ++mm) {
#pragma unroll
            for (int r = 0; r < 4; ++r) {
                float s0 = 0.f, s1 = 0.f;
#pragma unroll
                for (int nn = 0; nn < 4; ++nn) {
                    float v = acc[mm][nn][r];
                    s0 = fmaf(v, a0v[nn], s0);
                    s1 = fmaf(v, a1v[nn], s1);
                }
#pragma unroll
                for (int off = 1; off < 16; off <<= 1) {
                    s0 += __shfl_xor(s0, off, 64);
                    s1 += __shfl_xor(s1, off, 64);
                }
                int grow = row0 + wm*32 + mm*16 + quad*4 + r;
                if (lrow == 0 && grow < M) {
                    srcdot[(size_t)grow*8 + head] = s0;
                    dstdot[(size_t)grow*8 + head] = s1;
                }
            }
        }
    }

#pragma unroll
    for (int mm = 0; mm < 2; ++mm) {
        int rbase = row0 + wm*32 + mm*16 + quad*4;
#pragma unroll
        for (int nn = 0; nn < 4; ++nn) {
            int c = col0 + wn*64 + nn*16 + lrow;
            int off = (c & 63)*8 + (c >> 6);     // permuted layout
#pragma unroll
            for (int r = 0; r < 4; ++r) {
                int grow = rbase + r;
                if (grow < M)
                    H1p[(size_t)grow*512 + off] = f2bf(acc[mm][nn][r]);
            }
        }
    }
}

// ---------------------------------------------------------------------------
// Layer-2 MFMA GEMM with FUSED final dots — 8-wave occupancy version.
// 512 threads, 128x64 tile (grid 391), each wave owns 16 rows x ALL 64 cols
// (acc[4] = 16 regs), so the dots epilogue stays wave-local.
__global__ __launch_bounds__(512, 4) void mfma_gemm2(const unsigned short* __restrict__ Abf,
                                                  const unsigned short* __restrict__ Bbf,
                                                  const float* __restrict__ a_out,
                                                  float* __restrict__ H2p,
                                                  float* __restrict__ src2,
                                                  float* __restrict__ dst2, int M) {
    __shared__ short Asl[128*40];
    __shared__ short Bsl[64*40];
    int tid  = threadIdx.x;
    int wid  = tid >> 6, lane = tid & 63;
    int lrow = lane & 15, quad = lane >> 4;
    int row0 = blockIdx.x * 128;
    if (row0 >= M) return;

    int sr = tid >> 2, sk = (tid & 3) * 8;     // A: 128 rows x 32 k
    int ar = row0 + sr; ar = ar < M ? ar : M - 1;
    int sr2 = (tid & 255) >> 2, sk2 = (tid & 3) * 8;   // B: 64 rows x 32 k (tid<256)

    floatx4 acc[4];
#pragma unroll
    for (int nn = 0; nn < 4; nn++) acc[nn] = (floatx4){0.f,0.f,0.f,0.f};

    short8 fa, fbv;
    fa = *(const short8*)(Abf + (size_t)ar*512 + sk);
    if (tid < 256)
        fbv = *(const short8*)(Bbf + (size_t)sr2*512 + sk2);

    for (int k0 = 0; k0 < 512; k0 += 32) {
        *(short8*)(&Asl[sr*40 + sk]) = fa;
        if (tid < 256)
            *(short8*)(&Bsl[sr2*40 + sk2]) = fbv;
        __syncthreads();
        if (k0 + 32 < 512) {
            int kn = k0 + 32;
            fa = *(const short8*)(Abf + (size_t)ar*512 + kn + sk);
            if (tid < 256)
                fbv = *(const short8*)(Bbf + (size_t)sr2*512 + kn + sk2);
        }
        short8 af, bfr[4];
        af = *(const short8*)(&Asl[(wid*16 + lrow)*40 + quad*8]);
#pragma unroll
        for (int nn = 0; nn < 4; ++nn)
            bfr[nn] = *(const short8*)(&Bsl[(nn*16 + lrow)*40 + quad*8]);
#pragma unroll
        for (int nn = 0; nn < 4; ++nn)
            acc[nn] = __builtin_amdgcn_mfma_f32_16x16x32_bf16(
                af, bfr[nn], acc[nn], 0, 0, 0);
        __syncthreads();
    }

    // ---- fused final attention dots (cols 40..63 of acc are exactly 0) ----
    {
        float a0v[4], a1v[4];
#pragma unroll
        for (int nn = 0; nn < 4; ++nn) {
            int c = nn*16 + lrow;
            a0v[nn] = c < NCLASS ? a_out[c] : 0.f;
            a1v[nn] = c < NCLASS ? a_out[NCLASS + c] : 0.f;
        }
#pragma unroll
        for (int r = 0; r < 4; ++r) {
            float s0 = 0.f, s1 = 0.f;
#pragma unroll
            for (int nn = 0; nn < 4; ++nn) {
                float v = acc[nn][r];
                s0 = fmaf(v, a0v[nn], s0);
                s1 = fmaf(v, a1v[nn], s1);
            }
#pragma unroll
            for (int off = 1; off < 16; off <<= 1) {
                s0 += __shfl_xor(s0, off, 64);
                s1 += __shfl_xor(s1, off, 64);
            }
            int grow = row0 + wid*16 + quad*4 + r;
            if (lrow == 0 && grow < M) {
                src2[grow] = s0;
                dst2[grow] = s1;
            }
        }
    }

#pragma unroll
    for (int nn = 0; nn < 4; ++nn) {
        int c = nn*16 + lrow;
#pragma unroll
        for (int r = 0; r < 4; ++r) {
            int grow = row0 + wid*16 + quad*4 + r;
            if (grow < M)
                H2p[(size_t)grow*64 + c] = acc[nn][r];
        }
    }
}

// ---------------------------------------------------------------------------
// CSR build
__global__ void histk(const int* __restrict__ row, int* __restrict__ deg) {
    int e = blockIdx.x*256 + threadIdx.x;
    if (e < N_EDGES) atomicAdd(&deg[row[e]], 1);
}
__global__ void scanA(const int* __restrict__ deg, int* __restrict__ row_ptr,
                      int* __restrict__ chunk_tot) {
    __shared__ int s[256];
    int t = threadIdx.x;
    int idx = blockIdx.x*256 + t;
    int v = (idx < N_NODES) ? deg[idx] : 0;
    s[t] = v;
    __syncthreads();
#pragma unroll
    for (int off = 1; off < 256; off <<= 1) {
        int x = (t >= off) ? s[t-off] : 0;
        __syncthreads();
        s[t] += x;
        __syncthreads();
    }
    if (idx < N_NODES) row_ptr[idx] = s[t] - v;
    if (t == 255) chunk_tot[blockIdx.x] = s[t];
}
__global__ void scanB(const int* __restrict__ chunk_tot, int* __restrict__ chunk_off,
                      int* __restrict__ row_ptr) {
    __shared__ int s[256];
    int t = threadIdx.x;
    int v = (t < NCHUNK) ? chunk_tot[t] : 0;
    s[t] = v;
    __syncthreads();
#pragma unroll
    for (int off = 1; off < 256; off <<= 1) {
        int x = (t >= off) ? s[t-off] : 0;
        __syncthreads();
        s[t] += x;
        __syncthreads();
    }
    if (t < NCHUNK) chunk_off[t] = s[t] - v;
    if (t == 255) row_ptr[N_NODES] = s[t];
}
__global__ void scanC(const int* __restrict__ chunk_off, int* __restrict__ row_ptr,
                      int* __restrict__ cursor) {
    int idx = blockIdx.x*256 + threadIdx.x;
    if (idx < N_NODES) {
        int rp = row_ptr[idx] + chunk_off[idx >> 8];
        row_ptr[idx] = rp;
        cursor[idx] = rp;
    }
}

// Fused CSR fill + layer-1 edge weights, stored in CSR slot order.
__global__ void fillk_w1(const int* __restrict__ row, const int* __restrict__ col,
                         const float* __restrict__ srcdot, const float* __restrict__ dstdot,
                         int* __restrict__ cursor, int* __restrict__ csr_col,
                         float* __restrict__ Wcsr) {
    int e = blockIdx.x*256 + threadIdx.x;
    if (e >= N_EDGES) return;
    int r = row[e], c = col[e];
    int pos = atomicAdd(&cursor[r], 1);
    csr_col[pos] = c;
    float4 sa = *(const float4*)(srcdot + (size_t)r*8);
    float4 sb = *(const float4*)(srcdot + (size_t)r*8 + 4);
    float4 da = *(const float4*)(dstdot + (size_t)c*8);
    float4 db = *(const float4*)(dstdot + (size_t)c*8 + 4);
    float s[8] = {sa.x+da.x, sa.y+da.y, sa.z+da.z, sa.w+da.w,
                  sb.x+db.x, sb.y+db.y, sb.z+db.z, sb.w+db.w};
    float o[8];
#pragma unroll
    for (int j = 0; j < 8; j++) {
        float lr = s[j] > 0.f ? s[j] : ALPHA*s[j];
        o[j] = __expf(-lr);
    }
    *(float4*)(Wcsr + (size_t)pos*8)     = make_float4(o[0], o[1], o[2], o[3]);
    *(float4*)(Wcsr + (size_t)pos*8 + 4) = make_float4(o[4], o[5], o[6], o[7]);
}

// ---------------------------------------------------------------------------
// Layer-1 aggregation + ELU. Wave per node; ONE 16-B gather per edge per lane;
// 4-edge unroll keeps 4 gathers in flight. (Round-0 form: best measured —
// deeper pipelining/readlane was neutral: agg1 is L3-fabric-fetch-bound,
// FETCH ~389MB vs ~346MB structural floor.)
__global__ __launch_bounds__(256) void agg1(const unsigned short* __restrict__ H1p,
                                            const float* __restrict__ Wcsr,
                                            const int* __restrict__ row_ptr,
                                            const int* __restrict__ csr_col,
                                            unsigned short* __restrict__ hcatb) {
    int wave = (blockIdx.x*256 + threadIdx.x) >> 6;
    int lane = threadIdx.x & 63;
    if (wave >= N_NODES) return;
    int start = row_ptr[wave], end = row_ptr[wave+1];
    float acc[8], den[8];
#pragma unroll
    for (int j = 0; j < 8; j++) { acc[j] = 0.f; den[j] = 0.f; }

    int k = start;
    for (; k + 4 <= end; k += 4) {
        int c0 = csr_col[k],   c1 = csr_col[k+1];
        int c2 = csr_col[k+2], c3 = csr_col[k+3];
        short8 hv0 = *(const short8*)(H1p + (size_t)c0*512 + lane*8);
        short8 hv1 = *(const short8*)(H1p + (size_t)c1*512 + lane*8);
        short8 hv2 = *(const short8*)(H1p + (size_t)c2*512 + lane*8);
        short8 hv3 = *(const short8*)(H1p + (size_t)c3*512 + lane*8);
        float4 wv[8];
#pragma unroll
        for (int q = 0; q < 8; q++)
            wv[q] = *(const float4*)(Wcsr + (size_t)k*8 + q*4);
        const float* w0 = (const float*)&wv[0];
        const float* w1 = (const float*)&wv[2];
        const float* w2 = (const float*)&wv[4];
        const float* w3 = (const float*)&wv[6];
#pragma unroll
        for (int j = 0; j < 8; j++) {
            den[j] += (w0[j] + w1[j]) + (w2[j] + w3[j]);
            acc[j] = fmaf(w0[j], bf2f((unsigned short)hv0[j]), acc[j]);
            acc[j] = fmaf(w1[j], bf2f((unsigned short)hv1[j]), acc[j]);
            acc[j] = fmaf(w2[j], bf2f((unsigned short)hv2[j]), acc[j]);
            acc[j] = fmaf(w3[j], bf2f((unsigned short)hv3[j]), acc[j]);
        }
    }
    for (; k < end; ++k) {
        int c = csr_col[k];
        float4 wa = *(const float4*)(Wcsr + (size_t)k*8);
        float4 wb = *(const float4*)(Wcsr + (size_t)k*8 + 4);
        short8 hv = *(const short8*)(H1p + (size_t)c*512 + lane*8);
        float w[8] = {wa.x, wa.y, wa.z, wa.w, wb.x, wb.y, wb.z, wb.w};
#pragma unroll
        for (int j = 0; j < 8; j++) {
            den[j] += w[j];
            acc[j] = fmaf(w[j], bf2f((unsigned short)hv[j]), acc[j]);
        }
    }
#pragma unroll
    for (int j = 0; j < 8; j++) {
        float o = acc[j] / (den[j] + EPS_F);
        o = o > 0.f ? o : (__expf(o) - 1.f);   // ELU
        hcatb[(size_t)wave*HD + j*64 + lane] = f2bf(o);
    }
}

// ---------------------------------------------------------------------------
// Final aggregation, software-pipelined (8-edge x 2-color batches;
// per-edge state is 2 floats so registers stay cheap).
__global__ __launch_bounds__(256) void agg2(const float* __restrict__ H2p,
                                            const float* __restrict__ src2,
                                            const float* __restrict__ dst2,
                                            const int* __restrict__ row_ptr,
                                            const int* __restrict__ csr_col,
                                            float* __restrict__ out) {
    int wave = (blockIdx.x*256 + threadIdx.x) >> 6;
    int lane = threadIdx.x & 63;
    if (wave >= N_NODES) return;
    int start = row_ptr[wave], end = row_ptr[wave+1];
    int deg = end - start;
    float s2i = src2[wave];
    int l = lane < NCLASS ? lane : 0;
    float acc = 0.f, den = 0.f;

    int colreg = 0;
    if (deg > 0) colreg = csr_col[start + (lane < deg ? lane : deg - 1)];

#define AG2_G1(T, H, IDX) do { \
    int cg_ = __builtin_amdgcn_readlane(colreg, (IDX)); \
    T = dst2[cg_]; \
    H = H2p[(size_t)cg_*64 + l]; \
} while(0)
#define AG2_C1(T, H) do { \
    float t_ = s2i + (T); \
    t_ = t_ > 0.f ? t_ : ALPHA*t_; \
    float w_ = __expf(-t_); \
    den += w_; acc = fmaf(w_, (H), acc); \
} while(0)
#define AG2_G8(T0,T1,T2,T3,T4,T5,T6,T7,H0,H1,H2,H3,H4,H5,H6,H7,BASE) do { \
    AG2_G1(T0,H0,(BASE));   AG2_G1(T1,H1,(BASE)+1); \
    AG2_G1(T2,H2,(BASE)+2); AG2_G1(T3,H3,(BASE)+3); \
    AG2_G1(T4,H4,(BASE)+4); AG2_G1(T5,H5,(BASE)+5); \
    AG2_G1(T6,H6,(BASE)+6); AG2_G1(T7,H7,(BASE)+7); \
} while(0)
#define AG2_C8(T0,T1,T2,T3,T4,T5,T6,T7,H0,H1,H2,H3,H4,H5,H6,H7) do { \
    AG2_C1(T0,H0); AG2_C1(T1,H1); AG2_C1(T2,H2); AG2_C1(T3,H3); \
    AG2_C1(T4,H4); AG2_C1(T5,H5); AG2_C1(T6,H6); AG2_C1(T7,H7); \
} while(0)

    int lim = deg < 64 ? deg : 64;
    int nb = lim >> 3;
    int k = start;
    float ta0,ta1,ta2,ta3,ta4,ta5,ta6,ta7, ga0,ga1,ga2,ga3,ga4,ga5,ga6,ga7;
    float tb0,tb1,tb2,tb3,tb4,tb5,tb6,tb7, gb0,gb1,gb2,gb3,gb4,gb5,gb6,gb7;
    if (nb > 0) {
        AG2_G8(ta0,ta1,ta2,ta3,ta4,ta5,ta6,ta7, ga0,ga1,ga2,ga3,ga4,ga5,ga6,ga7, 0);
        int b = 1;
        for (; b + 1 < nb; b += 2) {
            AG2_G8(tb0,tb1,tb2,tb3,tb4,tb5,tb6,tb7, gb0,gb1,gb2,gb3,gb4,gb5,gb6,gb7, b*8);
            AG2_C8(ta0,ta1,ta2,ta3,ta4,ta5,ta6,ta7, ga0,ga1,ga2,ga3,ga4,ga5,ga6,ga7);
            AG2_G8(ta0,ta1,ta2,ta3,ta4,ta5,ta6,ta7, ga0,ga1,ga2,ga3,ga4,ga5,ga6,ga7, (b+1)*8);
            AG2_C8(tb0,tb1,tb2,tb3,tb4,tb5,tb6,tb7, gb0,gb1,gb2,gb3,gb4,gb5,gb6,gb7);
        }
        if (b < nb) {
            AG2_G8(tb0,tb1,tb2,tb3,tb4,tb5,tb6,tb7, gb0,gb1,gb2,gb3,gb4,gb5,gb6,gb7, b*8);
            AG2_C8(ta0,ta1,ta2,ta3,ta4,ta5,ta6,ta7, ga0,ga1,ga2,ga3,ga4,ga5,ga6,ga7);
            AG2_C8(tb0,tb1,tb2,tb3,tb4,tb5,tb6,tb7, gb0,gb1,gb2,gb3,gb4,gb5,gb6,gb7);
        } else {
            AG2_C8(ta0,ta1,ta2,ta3,ta4,ta5,ta6,ta7, ga0,ga1,ga2,ga3,ga4,ga5,ga6,ga7);
        }
        k = start + nb*8;
    }
    for (; k < end; ++k) {
        int c_ = (k - start < 64) ? __builtin_amdgcn_readlane(colreg, k - start)
                                  : csr_col[k];
        float t = dst2[c_];
        float h = H2p[(size_t)c_*64 + l];
        AG2_C1(t, h);
    }
#undef AG2_G1
#undef AG2_C1
#undef AG2_G8
#undef AG2_C8

    if (lane < NCLASS)
        out[(size_t)wave*NCLASS + lane] = acc / (den + EPS_F);
}

// ---------------------------------------------------------------------------
extern "C" void kernel_launch(void* const* d_in, const int* in_sizes, int n_in,
                              void* d_out, int out_size, void* d_ws, size_t ws_size,
                              hipStream_t stream) {
    const float* x       = (const float*)d_in[0];
    const float* W_heads = (const float*)d_in[1];
    const float* a_heads = (const float*)d_in[2];
    const float* W_out   = (const float*)d_in[3];
    const float* a_out   = (const float*)d_in[4];
    const int*   ei      = (const int*)d_in[5];
    const int*   row     = ei;
    const int*   col     = ei + N_EDGES;
    float* out = (float*)d_out;

    char* ws = (char*)d_ws;
    size_t off = 0;
    auto alloc = [&](size_t bytes) {
        char* p = ws + off;
        off = (off + bytes + 255) & ~(size_t)255;
        return p;
    };
    unsigned short* Wrb   = (unsigned short*)alloc((size_t)512*512*2);
    unsigned short* Wob   = (unsigned short*)alloc((size_t)64*512*2);
    unsigned short* H1p   = (unsigned short*)alloc((size_t)N_NODES*HD*2);
    unsigned short* hcatb = (unsigned short*)alloc((size_t)N_NODES*HD*2);
    float* srcdot  = (float*)alloc((size_t)N_NODES*NHEADS*4);
    float* dstdot  = (float*)alloc((size_t)N_NODES*NHEADS*4);
    float* Wcsr    = (float*)alloc((size_t)N_EDGES*NHEADS*4);
    int*   deg     = (int*)alloc((size_t)N_NODES*4);
    int*   row_ptr = (int*)alloc((size_t)(N_NODES+1)*4);
    int*   cursor  = (int*)alloc((size_t)N_NODES*4);
    int*   ctot    = (int*)alloc(256*4);
    int*   coff    = (int*)alloc(256*4);
    int*   csr_col = (int*)alloc((size_t)N_EDGES*4);
    float* H2p     = (float*)alloc((size_t)N_NODES*64*4);
    float* src2    = (float*)alloc((size_t)N_NODES*4);
    float* dst2    = (float*)alloc((size_t)N_NODES*4);
    (void)ws_size;

    const int EB = (N_EDGES + 255)/256;
    const int WB = (N_NODES*64 + 255)/256;   // wave-per-node grids

    // Layer 1 (gemm1 also produces srcdot/dstdot)
    prep<<<(512*512 + 255)/256, 256, 0, stream>>>(W_heads, Wrb, W_out, Wob, deg);
    {
        int rtiles = (N_NODES + 127)/128;            // 391
        int nblk = ((rtiles + 7)/8) * 32;            // 1568
        mfma_gemm1<<<nblk, 512, 0, stream>>>(x, Wrb, a_heads, H1p,
                                             srcdot, dstdot, N_NODES);
    }

    // CSR build + fused layer-1 edge weights
    histk<<<EB, 256, 0, stream>>>(row, deg);
    scanA<<<NCHUNK, 256, 0, stream>>>(deg, row_ptr, ctot);
    scanB<<<1, 256, 0, stream>>>(ctot, coff, row_ptr);
    scanC<<<NCHUNK, 256, 0, stream>>>(coff, row_ptr, cursor);
    fillk_w1<<<EB, 256, 0, stream>>>(row, col, srcdot, dstdot, cursor,
                                     csr_col, Wcsr);

    agg1<<<WB, 256, 0, stream>>>(H1p, Wcsr, row_ptr, csr_col, hcatb);

    // Layer 2 (gemm2 also produces src2/dst2)
    mfma_gemm2<<<(N_NODES + 127)/128, 512, 0, stream>>>(hcatb, Wob, a_out,
                                                        H2p, src2, dst2, N_NODES);
    agg2<<<WB, 256, 0, stream>>>(H2p, src2, dst2, row_ptr, csr_col, out);
}